// Round 13
// baseline (257.369 us; speedup 1.0000x reference)
//
#include <hip/hip_runtime.h>
#include <hip/hip_bf16.h>
#include <math.h>

#define BB 8
#define CC 256
#define NN 2048
static constexpr float BN_EPS = 1e-5f;

typedef _Float16 f16;
typedef f16 f16x4 __attribute__((ext_vector_type(4)));
typedef f16 f16x8 __attribute__((ext_vector_type(8)));
typedef float f32x4 __attribute__((ext_vector_type(4)));
typedef short s16x8 __attribute__((ext_vector_type(8)));     // 8 bf16 (MFMA operand)
typedef unsigned short u16x8 __attribute__((ext_vector_type(8)));  // 16B raw
typedef __hip_bfloat16 bf16;

#define APAD 40   // 16-bit-elem row stride (32 data + 8 pad) = 80B, 16B-aligned
#define XPAD 72   // 16-bit-elem row stride (64 data + 8 pad) = 144B, 16B-aligned

// ---------------------------------------------------------------------------
// Prep A: four C x C weight matrices -> hi/lo f16 planes (concatenated).
// ---------------------------------------------------------------------------
__global__ __launch_bounds__(256) void prep_w_kernel(
    const float* __restrict__ Wq, const float* __restrict__ Wk,
    const float* __restrict__ Wv, const float* __restrict__ Wt,
    f16* __restrict__ Whi, f16* __restrict__ Wlo)
{
    int idx = (blockIdx.x * 256 + threadIdx.x) * 8;   // over 4*C*C
    const float* s = (idx < 65536) ? Wq : (idx < 131072) ? Wk
                    : (idx < 196608) ? Wv : Wt;
    int off = idx & 65535;
    float4 a = *(const float4*)&s[off];
    float4 b = *(const float4*)&s[off + 4];
    float v[8] = {a.x, a.y, a.z, a.w, b.x, b.y, b.z, b.w};
    f16x8 h, l;
#pragma unroll
    for (int j = 0; j < 8; ++j) {
        f16 hh = (f16)v[j];
        f16 ll = (f16)(v[j] - (float)hh);
        h[j] = hh;
        l[j] = ll;
    }
    *(f16x8*)&Whi[idx] = h;
    *(f16x8*)&Wlo[idx] = l;
}

// ---------------------------------------------------------------------------
// Prep B: Xhi/Xlo[b][n][c] = split (f16) of x[b][c][n]  (LDS-tiled transpose)
// ---------------------------------------------------------------------------
__global__ __launch_bounds__(256) void prep_x_kernel(
    const float* __restrict__ x, f16* __restrict__ Xhi, f16* __restrict__ Xlo)
{
    const int b = blockIdx.z, c0 = blockIdx.y * 64, n0 = blockIdx.x * 64;
    const float* __restrict__ Xb = x + (size_t)b * CC * NN;
    f16* __restrict__ Oh = Xhi + (size_t)b * NN * CC;
    f16* __restrict__ Ol = Xlo + (size_t)b * NN * CC;
    __shared__ f16 Th[64][72];
    __shared__ f16 Tl[64][72];
    const int tid = threadIdx.x;
    const int r = tid >> 4, c4 = (tid & 15) * 4;
#pragma unroll
    for (int i = 0; i < 4; ++i) {
        int rr = r + i * 16;
        float4 v = *(const float4*)&Xb[(size_t)(c0 + rr) * NN + n0 + c4];
        float vv[4] = {v.x, v.y, v.z, v.w};
#pragma unroll
        for (int j = 0; j < 4; ++j) {
            f16 hh = (f16)vv[j];
            f16 ll = (f16)(vv[j] - (float)hh);
            Th[c4 + j][rr] = hh;
            Tl[c4 + j][rr] = ll;
        }
    }
    __syncthreads();
#pragma unroll
    for (int i = 0; i < 2; ++i) {
        int idx = tid + 256 * i;
        int n = idx >> 3, cg = (idx & 7) * 8;
        *(f16x8*)&Oh[(size_t)(n0 + n) * CC + c0 + cg] = *(f16x8*)&Th[n][cg];
        *(f16x8*)&Ol[(size_t)(n0 + n) * CC + c0 + cg] = *(f16x8*)&Tl[n][cg];
    }
}

// ---------------------------------------------------------------------------
// Kernel 1: projections. Q/K: split-precision (hi*hi + hi*lo + lo*hi) ->
// f16 [b][n][c]. V: hi-only -> bf16 [b][c][n] (+bv).
// ---------------------------------------------------------------------------
__global__ __launch_bounds__(256) void proj_mfma_kernel(
    const f16* __restrict__ Whi, const f16* __restrict__ Wlo,
    const f16* __restrict__ Xhi, const f16* __restrict__ Xlo,
    const float* __restrict__ bv,
    f16* __restrict__ Qhi, f16* __restrict__ Khi, bf16* __restrict__ Vb16)
{
    const int which = blockIdx.z >> 3;
    const int b     = blockIdx.z & 7;
    const f16* __restrict__ Wh = Whi + (size_t)which * CC * CC;
    const f16* __restrict__ Wl = Wlo + (size_t)which * CC * CC;
    const f16* __restrict__ Xh = Xhi + (size_t)b * NN * CC;
    const f16* __restrict__ Xl = Xlo + (size_t)b * NN * CC;

    const int m0 = blockIdx.y * 128;   // output channels
    const int n0 = blockIdx.x * 128;   // points

    __shared__ f16 Ah[128 * APAD];
    __shared__ f16 Al[128 * APAD];
    __shared__ f16 Bh[128 * APAD];
    __shared__ f16 Bl[128 * APAD];

    const int tid = threadIdx.x;
    const int wave = tid >> 6, lane = tid & 63;
    const int wr = (wave >> 1) * 64, wc = (wave & 1) * 64;
    const int lrow = lane & 15, lk = (lane >> 4) * 8;

    f32x4 acc[4][4] = {};

    for (int k0 = 0; k0 < CC; k0 += 32) {
#pragma unroll
        for (int i = 0; i < 2; ++i) {
            int idx = tid + 256 * i;
            int r = idx >> 2, ch = idx & 3;
            *(f16x8*)&Ah[r * APAD + ch * 8] =
                *(const f16x8*)&Wh[(size_t)(m0 + r) * CC + k0 + ch * 8];
            *(f16x8*)&Bh[r * APAD + ch * 8] =
                *(const f16x8*)&Xh[(size_t)(n0 + r) * CC + k0 + ch * 8];
            if (which < 2) {
                *(f16x8*)&Al[r * APAD + ch * 8] =
                    *(const f16x8*)&Wl[(size_t)(m0 + r) * CC + k0 + ch * 8];
                *(f16x8*)&Bl[r * APAD + ch * 8] =
                    *(const f16x8*)&Xl[(size_t)(n0 + r) * CC + k0 + ch * 8];
            }
        }
        __syncthreads();
        f16x8 ah[4], al[4], bh[4], bl[4];
#pragma unroll
        for (int i = 0; i < 4; ++i) {
            ah[i] = *(const f16x8*)&Ah[(wr + i * 16 + lrow) * APAD + lk];
            bh[i] = *(const f16x8*)&Bh[(wc + i * 16 + lrow) * APAD + lk];
        }
        if (which < 2) {
#pragma unroll
            for (int i = 0; i < 4; ++i) {
                al[i] = *(const f16x8*)&Al[(wr + i * 16 + lrow) * APAD + lk];
                bl[i] = *(const f16x8*)&Bl[(wc + i * 16 + lrow) * APAD + lk];
            }
        }
#pragma unroll
        for (int i = 0; i < 4; ++i)
#pragma unroll
            for (int j = 0; j < 4; ++j) {
                acc[i][j] = __builtin_amdgcn_mfma_f32_16x16x32_f16(
                    ah[i], bh[j], acc[i][j], 0, 0, 0);
                if (which < 2) {
                    acc[i][j] = __builtin_amdgcn_mfma_f32_16x16x32_f16(
                        ah[i], bl[j], acc[i][j], 0, 0, 0);
                    acc[i][j] = __builtin_amdgcn_mfma_f32_16x16x32_f16(
                        al[i], bh[j], acc[i][j], 0, 0, 0);
                }
            }
        __syncthreads();
    }

    if (which < 2) {
        f16* __restrict__ Oh = ((which == 0) ? Qhi : Khi) + (size_t)b * NN * CC;
#pragma unroll
        for (int i = 0; i < 4; ++i) {
            int cb = m0 + wr + i * 16 + (lane >> 4) * 4;
#pragma unroll
            for (int j = 0; j < 4; ++j) {
                int n = n0 + wc + j * 16 + lrow;
                f16x4 hv;
#pragma unroll
                for (int q = 0; q < 4; ++q) hv[q] = (f16)acc[i][j][q];
                *(f16x4*)&Oh[(size_t)n * CC + cb] = hv;
            }
        }
    } else {
        bf16* __restrict__ Vb = Vb16 + (size_t)b * CC * NN;
#pragma unroll
        for (int i = 0; i < 4; ++i) {
            int cb = m0 + wr + i * 16 + (lane >> 4) * 4;
#pragma unroll
            for (int q = 0; q < 4; ++q) {
                float bvv = bv[cb + q];
#pragma unroll
                for (int j = 0; j < 4; ++j) {
                    int n = n0 + wc + j * 16 + lrow;
                    Vb[(size_t)(cb + q) * NN + n] = __float2bfloat16(acc[i][j][q] + bvv);
                }
            }
        }
    }
}

// ---------------------------------------------------------------------------
// Kernel 2: energy = Qhi . Khi^T -> fp32 logits (LDS-staged hi-only).
// ---------------------------------------------------------------------------
__global__ __launch_bounds__(256) void energy_mfma_kernel(
    const f16* __restrict__ Qhi, const f16* __restrict__ Khi,
    float* __restrict__ ATT)
{
    const int b = blockIdx.z;
    const int n0 = blockIdx.y * 128;
    const int m0 = blockIdx.x * 128;
    const f16* __restrict__ Qh = Qhi + (size_t)b * NN * CC;
    const f16* __restrict__ Kh = Khi + (size_t)b * NN * CC;
    float* __restrict__ Eb = ATT + (size_t)b * NN * NN;

    __shared__ f16 Ah[128 * APAD];
    __shared__ f16 Bh[128 * APAD];

    const int tid = threadIdx.x;
    const int wave = tid >> 6, lane = tid & 63;
    const int wr = (wave >> 1) * 64, wc = (wave & 1) * 64;
    const int lrow = lane & 15, lk = (lane >> 4) * 8;

    f32x4 acc[4][4] = {};

    for (int k0 = 0; k0 < CC; k0 += 32) {
#pragma unroll
        for (int i = 0; i < 2; ++i) {
            int idx = tid + 256 * i;
            int r = idx >> 2, ch = idx & 3;
            *(f16x8*)&Ah[r * APAD + ch * 8] =
                *(const f16x8*)&Qh[(size_t)(n0 + r) * CC + k0 + ch * 8];
            *(f16x8*)&Bh[r * APAD + ch * 8] =
                *(const f16x8*)&Kh[(size_t)(m0 + r) * CC + k0 + ch * 8];
        }
        __syncthreads();
        f16x8 af[4], bf[4];
#pragma unroll
        for (int i = 0; i < 4; ++i) {
            af[i] = *(const f16x8*)&Ah[(wr + i * 16 + lrow) * APAD + lk];
            bf[i] = *(const f16x8*)&Bh[(wc + i * 16 + lrow) * APAD + lk];
        }
#pragma unroll
        for (int i = 0; i < 4; ++i)
#pragma unroll
            for (int j = 0; j < 4; ++j)
                acc[i][j] = __builtin_amdgcn_mfma_f32_16x16x32_f16(
                    af[i], bf[j], acc[i][j], 0, 0, 0);
        __syncthreads();
    }

#pragma unroll
    for (int i = 0; i < 4; ++i)
#pragma unroll
        for (int q = 0; q < 4; ++q) {
            int row = n0 + wr + i * 16 + (lane >> 4) * 4 + q;
#pragma unroll
            for (int j = 0; j < 4; ++j) {
                int col = m0 + wc + j * 16 + lrow;
                Eb[(size_t)row * NN + col] = acc[i][j][q];
            }
        }
}

// ---------------------------------------------------------------------------
// Kernel 3 (fused): row softmax + column sums + block-transposed bf16 store.
// (unchanged from round 12; descending-tile in-place clobber proof in place)
// ---------------------------------------------------------------------------
__global__ __launch_bounds__(1024) void softmax_cs_tr_kernel(
    float* __restrict__ ATT, float* __restrict__ colsum)
{
    const int b = blockIdx.y;
    const int n0s = blockIdx.x * 64;
    float* __restrict__ Eb = ATT + (size_t)b * NN * NN;
    bf16* __restrict__ A16 = (bf16*)Eb;

    __shared__ float smx[64], sinv[64];
    __shared__ bf16 T[4][64][72];

    const int tid = threadIdx.x;
    const int wave = tid >> 6, lane = tid & 63;

#pragma unroll
    for (int i = 0; i < 4; ++i) {
        const int row = wave * 4 + i;
        const float* __restrict__ R = &Eb[(size_t)(n0s + row) * NN];
        float4 e4[8];
#pragma unroll
        for (int c = 0; c < 8; ++c)
            e4[c] = *(const float4*)&R[c * 256 + lane * 4];
        float mx = -1e30f;
#pragma unroll
        for (int c = 0; c < 8; ++c)
            mx = fmaxf(mx, fmaxf(fmaxf(e4[c].x, e4[c].y), fmaxf(e4[c].z, e4[c].w)));
#pragma unroll
        for (int d = 1; d < 64; d <<= 1) mx = fmaxf(mx, __shfl_xor(mx, d));
        float s = 0.f;
#pragma unroll
        for (int c = 0; c < 8; ++c)
            s += __expf(e4[c].x - mx) + __expf(e4[c].y - mx)
               + __expf(e4[c].z - mx) + __expf(e4[c].w - mx);
#pragma unroll
        for (int d = 1; d < 64; d <<= 1) s += __shfl_xor(s, d);
        if (lane == 0) { smx[row] = mx; sinv[row] = 1.f / s; }
    }
    __syncthreads();

    const int g = tid >> 8, t = tid & 255;
    for (int rd = 0; rd < 8; ++rd) {
        const int mt = 28 - 4 * rd + g;
        const int m0 = mt * 64;
#pragma unroll
        for (int i = 0; i < 4; ++i) {
            int idx = t + 256 * i;
            int nl = idx >> 4, mc = (idx & 15) * 4;
            float4 v = *(const float4*)&Eb[(size_t)(n0s + nl) * NN + m0 + mc];
            float mx = smx[nl], iv = sinv[nl];
            T[g][mc + 0][nl] = __float2bfloat16(__expf(v.x - mx) * iv);
            T[g][mc + 1][nl] = __float2bfloat16(__expf(v.y - mx) * iv);
            T[g][mc + 2][nl] = __float2bfloat16(__expf(v.z - mx) * iv);
            T[g][mc + 3][nl] = __float2bfloat16(__expf(v.w - mx) * iv);
        }
        __syncthreads();
        {
            int ml = t >> 2, q = t & 3;
            float cs = 0.f;
#pragma unroll
            for (int j = 0; j < 16; ++j)
                cs += __bfloat162float(T[g][ml][q * 16 + j]);
            cs += __shfl_xor(cs, 1);
            cs += __shfl_xor(cs, 2);
            if (q == 0) atomicAdd(&colsum[b * NN + m0 + ml], cs);
        }
#pragma unroll
        for (int i = 0; i < 2; ++i) {
            int idx = t + 256 * i;
            int mr = idx >> 3, ch = idx & 7;
            u16x8 w = *(const u16x8*)&T[g][mr][ch * 8];
            *(u16x8*)&A16[(size_t)(n0s + mr) * (2 * NN) + NN + m0 + ch * 8] = w;
        }
        __syncthreads();
    }
}

// ---------------------------------------------------------------------------
// Kernel 5a: split-K x_r partials. z = b*2 + half; each block contracts
// K in [half*1024, half*1024+1024) over a 64x64 tile and writes its fp32
// partial to P[half] — 2048 blocks -> 8 blocks/CU resident (32 waves/CU).
// ---------------------------------------------------------------------------
__global__ __launch_bounds__(256) void xr_split_kernel(
    const bf16* __restrict__ Vb16, const float* __restrict__ ATT,
    float* __restrict__ P0, float* __restrict__ P1)
{
    const int z = blockIdx.z;
    const int b = z >> 1, half = z & 1;
    const int c0 = blockIdx.y * 64;
    const int n0 = blockIdx.x * 64;
    const bf16* __restrict__ Vb = Vb16 + (size_t)b * CC * NN;
    const bf16* __restrict__ A16 = (const bf16*)(ATT + (size_t)b * NN * NN);
    float* __restrict__ P = ((half == 0) ? P0 : P1) + (size_t)b * CC * NN;

    __shared__ bf16 Asl[64 * XPAD];
    __shared__ bf16 Bsl[64 * XPAD];

    const int tid = threadIdx.x;
    const int wave = tid >> 6, lane = tid & 63;
    const int wr = (wave >> 1) * 32, wc = (wave & 1) * 32;
    const int lrow = lane & 15, lk = (lane >> 4) * 8;

    f32x4 acc[2][2] = {};

    const int kbeg = half * 1024, kend = kbeg + 1024;
    for (int k0 = kbeg; k0 < kend; k0 += 64) {
#pragma unroll
        for (int i = 0; i < 2; ++i) {
            int idx = tid + 256 * i;
            int r = idx >> 3, ch = idx & 7;
            *(u16x8*)&Asl[r * XPAD + ch * 8] =
                *(const u16x8*)&Vb[(size_t)(c0 + r) * NN + k0 + ch * 8];
            *(u16x8*)&Bsl[r * XPAD + ch * 8] =
                *(const u16x8*)&A16[(size_t)(k0 + r) * (2 * NN) + NN + n0 + ch * 8];
        }
        __syncthreads();
#pragma unroll
        for (int ks = 0; ks < 2; ++ks) {
            s16x8 af[2], bf[2];
#pragma unroll
            for (int i = 0; i < 2; ++i) {
                af[i] = *(const s16x8*)&Asl[(wr + i * 16 + lrow) * XPAD + ks * 32 + lk];
                bf[i] = *(const s16x8*)&Bsl[(wc + i * 16 + lrow) * XPAD + ks * 32 + lk];
            }
#pragma unroll
            for (int i = 0; i < 2; ++i)
#pragma unroll
                for (int j = 0; j < 2; ++j)
                    acc[i][j] = __builtin_amdgcn_mfma_f32_16x16x32_bf16(
                        af[i], bf[j], acc[i][j], 0, 0, 0);
        }
        __syncthreads();
    }

#pragma unroll
    for (int i = 0; i < 2; ++i) {
        int cb = c0 + wr + i * 16 + (lane >> 4) * 4;
#pragma unroll
        for (int j = 0; j < 2; ++j) {
            int n = n0 + wc + j * 16 + lrow;
#pragma unroll
            for (int q = 0; q < 4; ++q)
                P[(size_t)(cb + q) * NN + n] = acc[i][j][q];
        }
    }
}

// ---------------------------------------------------------------------------
// Kernel 5b: combine partials: Dt16[n][c] = (f16)(x[c][n] - (P0+P1)[c][n]*rcv[n])
// Coalesced reads along n, LDS transpose, coalesced f16 writes along c.
// ---------------------------------------------------------------------------
__global__ __launch_bounds__(256) void xrd_kernel(
    const float* __restrict__ P0, const float* __restrict__ P1,
    const float* __restrict__ colsum, const float* __restrict__ x,
    f16* __restrict__ Dt16)
{
    const int b = blockIdx.z;
    const int c0 = blockIdx.y * 64;
    const int n0 = blockIdx.x * 64;
    const float* __restrict__ Xb = x + (size_t)b * CC * NN;
    const float* __restrict__ Pa = P0 + (size_t)b * CC * NN;
    const float* __restrict__ Pb = P1 + (size_t)b * CC * NN;
    f16* __restrict__ Db = Dt16 + (size_t)b * NN * CC;

    __shared__ f16 T[64][72];
    __shared__ float rcvL[64];

    const int tid = threadIdx.x;
    if (tid < 64) rcvL[tid] = 1.f / (1e-9f + colsum[b * NN + n0 + tid]);
    __syncthreads();

    const int r = tid >> 4, c4 = (tid & 15) * 4;
#pragma unroll
    for (int i = 0; i < 4; ++i) {
        int cc = r + i * 16;
        size_t off = (size_t)(c0 + cc) * NN + n0 + c4;
        float4 xv = *(const float4*)&Xb[off];
        float4 p0 = *(const float4*)&Pa[off];
        float4 p1 = *(const float4*)&Pb[off];
        float xa[4] = {xv.x, xv.y, xv.z, xv.w};
        float pa[4] = {p0.x, p0.y, p0.z, p0.w};
        float pb[4] = {p1.x, p1.y, p1.z, p1.w};
#pragma unroll
        for (int j = 0; j < 4; ++j)
            T[c4 + j][cc] = (f16)(xa[j] - (pa[j] + pb[j]) * rcvL[c4 + j]);
    }
    __syncthreads();
#pragma unroll
    for (int i = 0; i < 2; ++i) {
        int idx = tid + 256 * i;
        int nl = idx >> 3, cg = (idx & 7) * 8;
        *(f16x8*)&Db[(size_t)(n0 + nl) * CC + c0 + cg] = *(f16x8*)&T[nl][cg];
    }
}

// ---------------------------------------------------------------------------
// Kernel 6: XZ(bf16) = alpha*(Wt*Dt16 + bt) + beta; BN sums from fp32 values.
// ---------------------------------------------------------------------------
__global__ __launch_bounds__(256) void xz_mfma_kernel(
    const f16* __restrict__ Whi, const f16* __restrict__ Dt16,
    const float* __restrict__ bt, const float* __restrict__ alpha,
    const float* __restrict__ beta, bf16* __restrict__ XZ,
    float* __restrict__ bnsum, float* __restrict__ bnsumsq)
{
    const int b = blockIdx.z;
    const int m0 = blockIdx.y * 128;
    const int n0 = blockIdx.x * 128;
    const f16* __restrict__ Wb = Whi + (size_t)3 * CC * CC;   // Wt (hi)
    const f16* __restrict__ Db = Dt16 + (size_t)b * NN * CC;
    bf16* __restrict__ Zb = XZ + (size_t)b * CC * NN;

    __shared__ f16 Asl[128 * APAD];
    __shared__ f16 Bsl[128 * APAD];

    const int tid = threadIdx.x;
    const int wave = tid >> 6, lane = tid & 63;
    const int wr = (wave >> 1) * 64, wc = (wave & 1) * 64;
    const int lrow = lane & 15, lk = (lane >> 4) * 8;

    f32x4 acc[4][4] = {};

    for (int k0 = 0; k0 < CC; k0 += 32) {
#pragma unroll
        for (int i = 0; i < 2; ++i) {
            int idx = tid + 256 * i;
            int r = idx >> 2, ch = idx & 3;
            *(f16x8*)&Asl[r * APAD + ch * 8] =
                *(const f16x8*)&Wb[(size_t)(m0 + r) * CC + k0 + ch * 8];
            *(f16x8*)&Bsl[r * APAD + ch * 8] =
                *(const f16x8*)&Db[(size_t)(n0 + r) * CC + k0 + ch * 8];
        }
        __syncthreads();
        f16x8 af[4], bf[4];
#pragma unroll
        for (int i = 0; i < 4; ++i) {
            af[i] = *(const f16x8*)&Asl[(wr + i * 16 + lrow) * APAD + lk];
            bf[i] = *(const f16x8*)&Bsl[(wc + i * 16 + lrow) * APAD + lk];
        }
#pragma unroll
        for (int i = 0; i < 4; ++i)
#pragma unroll
            for (int j = 0; j < 4; ++j)
                acc[i][j] = __builtin_amdgcn_mfma_f32_16x16x32_f16(
                    af[i], bf[j], acc[i][j], 0, 0, 0);
        __syncthreads();
    }

#pragma unroll
    for (int i = 0; i < 4; ++i) {
#pragma unroll
        for (int q = 0; q < 4; ++q) {
            int o = m0 + wr + i * 16 + (lane >> 4) * 4 + q;
            float al = alpha[o], be = beta[o], bb = bt[o];
            float s1 = 0.f, s2 = 0.f;
#pragma unroll
            for (int j = 0; j < 4; ++j) {
                int n = n0 + wc + j * 16 + lrow;
                float z = al * (acc[i][j][q] + bb) + be;
                Zb[(size_t)o * NN + n] = __float2bfloat16(z);
                s1 += z; s2 += z * z;
            }
#pragma unroll
            for (int d = 1; d < 16; d <<= 1) {
                s1 += __shfl_xor(s1, d);
                s2 += __shfl_xor(s2, d);
            }
            if (lrow == 0) {
                atomicAdd(&bnsum[o], s1);
                atomicAdd(&bnsumsq[o], s2);
            }
        }
    }
}

// ---------------------------------------------------------------------------
// Kernel 7: out = x + relu(gamma*(XZ-mean)*rsqrt(var+eps)+beta)
// ---------------------------------------------------------------------------
__global__ __launch_bounds__(256) void final_kernel(
    const float* __restrict__ x, const bf16* __restrict__ XZ,
    const float* __restrict__ bnsum, const float* __restrict__ bnsumsq,
    const float* __restrict__ gamma, const float* __restrict__ bbeta,
    float* __restrict__ out)
{
    const int i4 = blockIdx.x * 256 + threadIdx.x;
    const int elem = i4 * 4;
    const int c = (elem / NN) % CC;
    const float inv_cnt = 1.f / (float)(BB * NN);
    const float mean = bnsum[c] * inv_cnt;
    const float var  = bnsumsq[c] * inv_cnt - mean * mean;
    const float rs = rsqrtf(var + BN_EPS);
    const float g = gamma[c], bb = bbeta[c];

    ushort4 zu = *(const ushort4*)&XZ[elem];
    float4 xv = *(const float4*)&x[elem];
    float z0 = __uint_as_float((unsigned)zu.x << 16);
    float z1 = __uint_as_float((unsigned)zu.y << 16);
    float z2 = __uint_as_float((unsigned)zu.z << 16);
    float z3 = __uint_as_float((unsigned)zu.w << 16);
    float4 o;
    o.x = xv.x + fmaxf(g * (z0 - mean) * rs + bb, 0.f);
    o.y = xv.y + fmaxf(g * (z1 - mean) * rs + bb, 0.f);
    o.z = xv.z + fmaxf(g * (z2 - mean) * rs + bb, 0.f);
    o.w = xv.w + fmaxf(g * (z3 - mean) * rs + bb, 0.f);
    *(float4*)&out[elem] = o;
}

// ---------------------------------------------------------------------------

extern "C" void kernel_launch(void* const* d_in, const int* in_sizes, int n_in,
                              void* d_out, int out_size, void* d_ws, size_t ws_size,
                              hipStream_t stream) {
    const float* x     = (const float*)d_in[0];
    const float* Wq    = (const float*)d_in[1];
    const float* Wk    = (const float*)d_in[2];
    const float* Wv    = (const float*)d_in[3];
    const float* bv    = (const float*)d_in[4];
    const float* Wt    = (const float*)d_in[5];
    const float* bt    = (const float*)d_in[6];
    const float* gamma = (const float*)d_in[7];
    const float* bbeta = (const float*)d_in[8];
    const float* alpha = (const float*)d_in[9];
    const float* beta  = (const float*)d_in[10];
    float* out = (float*)d_out;

    const size_t BCN = (size_t)BB * CC * NN;   // 4,194,304 elements
    const size_t WSZ = (size_t)4 * CC * CC;    // 262,144

    f16* Whi = (f16*)d_ws;                     // 4 x [C][C] hi
    f16* Wlo = Whi + WSZ;                      // 4 x [C][C] lo
    bf16* Vb16 = (bf16*)(Wlo + WSZ);           // [B][C][N] bf16
    f16* Qhi = (f16*)(Vb16 + BCN);             // [B][N][C]
    f16* Khi = Qhi + BCN;                      // [B][N][C]
    float* ATT = (float*)(Khi + BCN);          // [B][N][N]: fp32 logits, bf16 A^T in second halves
    bf16* XZ = (bf16*)(ATT + (size_t)BB * NN * NN);  // [B][C][N] bf16
    float* colsum  = (float*)(XZ + BCN);       // [B][N]
    float* bnsum   = colsum + (size_t)BB * NN; // [C]
    float* bnsumsq = bnsum + CC;               // [C]
    float* P1      = bnsumsq + CC;             // [B][C][N] fp32 partial (half 1)
    f16* Dt16      = (f16*)(P1 + BCN);         // [B][N][C] f16

    // P0 overlays Qhi+Khi (16.8 MB fp32, both dead after energy).
    float* P0 = (float*)Qhi;

    // Xhi/Xlo overlay batch-0's ATT slab (dead by the time energy writes it).
    f16* Xhi = (f16*)ATT;                      // [B][N][C]
    f16* Xlo = Xhi + BCN;                      // [B][N][C]

    hipMemsetAsync(colsum, 0, (size_t)(BB * NN + 2 * CC) * sizeof(float), stream);

    prep_w_kernel<<<dim3(4 * CC * CC / 2048), 256, 0, stream>>>(
        Wq, Wk, Wv, Wt, Whi, Wlo);
    prep_x_kernel<<<dim3(NN / 64, CC / 64, BB), 256, 0, stream>>>(x, Xhi, Xlo);
    proj_mfma_kernel<<<dim3(NN / 128, CC / 128, 3 * BB), 256, 0, stream>>>(
        Whi, Wlo, Xhi, Xlo, bv, Qhi, Khi, Vb16);
    energy_mfma_kernel<<<dim3(NN / 128, NN / 128, BB), 256, 0, stream>>>(
        Qhi, Khi, ATT);
    softmax_cs_tr_kernel<<<dim3(NN / 64, BB), 1024, 0, stream>>>(ATT, colsum);
    xr_split_kernel<<<dim3(NN / 64, CC / 64, 2 * BB), 256, 0, stream>>>(
        Vb16, ATT, P0, P1);
    xrd_kernel<<<dim3(NN / 64, CC / 64, BB), 256, 0, stream>>>(
        P0, P1, colsum, x, Dt16);
    xz_mfma_kernel<<<dim3(NN / 128, CC / 128, BB), 256, 0, stream>>>(
        Whi, Dt16, bt, alpha, beta, XZ, bnsum, bnsumsq);
    final_kernel<<<dim3((int)(BCN / 4 / 256)), 256, 0, stream>>>(
        x, XZ, bnsum, bnsumsq, gamma, bbeta, out);
}

// Round 14
// 244.907 us; speedup vs baseline: 1.0509x; 1.0509x over previous
//
#include <hip/hip_runtime.h>
#include <hip/hip_bf16.h>
#include <math.h>

#define BB 8
#define CC 256
#define NN 2048
static constexpr float BN_EPS = 1e-5f;

typedef _Float16 f16;
typedef f16 f16x4 __attribute__((ext_vector_type(4)));
typedef f16 f16x8 __attribute__((ext_vector_type(8)));
typedef float f32x4 __attribute__((ext_vector_type(4)));
typedef short s16x8 __attribute__((ext_vector_type(8)));     // 8 bf16 (MFMA operand)
typedef unsigned short u16x8 __attribute__((ext_vector_type(8)));  // 16B raw
typedef __hip_bfloat16 bf16;

#define APAD 40   // 16-bit-elem row stride (32 data + 8 pad) = 80B, 16B-aligned
#define XPAD 72   // 16-bit-elem row stride (64 data + 8 pad) = 144B, 16B-aligned

// ---------------------------------------------------------------------------
// Prep A: four C x C weight matrices -> hi/lo f16 planes (concatenated).
// ---------------------------------------------------------------------------
__global__ __launch_bounds__(256) void prep_w_kernel(
    const float* __restrict__ Wq, const float* __restrict__ Wk,
    const float* __restrict__ Wv, const float* __restrict__ Wt,
    f16* __restrict__ Whi, f16* __restrict__ Wlo)
{
    int idx = (blockIdx.x * 256 + threadIdx.x) * 8;   // over 4*C*C
    const float* s = (idx < 65536) ? Wq : (idx < 131072) ? Wk
                    : (idx < 196608) ? Wv : Wt;
    int off = idx & 65535;
    float4 a = *(const float4*)&s[off];
    float4 b = *(const float4*)&s[off + 4];
    float v[8] = {a.x, a.y, a.z, a.w, b.x, b.y, b.z, b.w};
    f16x8 h, l;
#pragma unroll
    for (int j = 0; j < 8; ++j) {
        f16 hh = (f16)v[j];
        f16 ll = (f16)(v[j] - (float)hh);
        h[j] = hh;
        l[j] = ll;
    }
    *(f16x8*)&Whi[idx] = h;
    *(f16x8*)&Wlo[idx] = l;
}

// ---------------------------------------------------------------------------
// Prep B: Xhi/Xlo[b][n][c] = split (f16) of x[b][c][n]  (LDS-tiled transpose)
// ---------------------------------------------------------------------------
__global__ __launch_bounds__(256) void prep_x_kernel(
    const float* __restrict__ x, f16* __restrict__ Xhi, f16* __restrict__ Xlo)
{
    const int b = blockIdx.z, c0 = blockIdx.y * 64, n0 = blockIdx.x * 64;
    const float* __restrict__ Xb = x + (size_t)b * CC * NN;
    f16* __restrict__ Oh = Xhi + (size_t)b * NN * CC;
    f16* __restrict__ Ol = Xlo + (size_t)b * NN * CC;
    __shared__ f16 Th[64][72];
    __shared__ f16 Tl[64][72];
    const int tid = threadIdx.x;
    const int r = tid >> 4, c4 = (tid & 15) * 4;
#pragma unroll
    for (int i = 0; i < 4; ++i) {
        int rr = r + i * 16;
        float4 v = *(const float4*)&Xb[(size_t)(c0 + rr) * NN + n0 + c4];
        float vv[4] = {v.x, v.y, v.z, v.w};
#pragma unroll
        for (int j = 0; j < 4; ++j) {
            f16 hh = (f16)vv[j];
            f16 ll = (f16)(vv[j] - (float)hh);
            Th[c4 + j][rr] = hh;
            Tl[c4 + j][rr] = ll;
        }
    }
    __syncthreads();
#pragma unroll
    for (int i = 0; i < 2; ++i) {
        int idx = tid + 256 * i;
        int n = idx >> 3, cg = (idx & 7) * 8;
        *(f16x8*)&Oh[(size_t)(n0 + n) * CC + c0 + cg] = *(f16x8*)&Th[n][cg];
        *(f16x8*)&Ol[(size_t)(n0 + n) * CC + c0 + cg] = *(f16x8*)&Tl[n][cg];
    }
}

// ---------------------------------------------------------------------------
// Kernel 1: projections. Q/K: split-precision (hi*hi + hi*lo + lo*hi) ->
// f16 [b][n][c]. V: hi-only -> bf16 [b][c][n] (+bv).
// ---------------------------------------------------------------------------
__global__ __launch_bounds__(256) void proj_mfma_kernel(
    const f16* __restrict__ Whi, const f16* __restrict__ Wlo,
    const f16* __restrict__ Xhi, const f16* __restrict__ Xlo,
    const float* __restrict__ bv,
    f16* __restrict__ Qhi, f16* __restrict__ Khi, bf16* __restrict__ Vb16)
{
    const int which = blockIdx.z >> 3;
    const int b     = blockIdx.z & 7;
    const f16* __restrict__ Wh = Whi + (size_t)which * CC * CC;
    const f16* __restrict__ Wl = Wlo + (size_t)which * CC * CC;
    const f16* __restrict__ Xh = Xhi + (size_t)b * NN * CC;
    const f16* __restrict__ Xl = Xlo + (size_t)b * NN * CC;

    const int m0 = blockIdx.y * 128;   // output channels
    const int n0 = blockIdx.x * 128;   // points

    __shared__ f16 Ah[128 * APAD];
    __shared__ f16 Al[128 * APAD];
    __shared__ f16 Bh[128 * APAD];
    __shared__ f16 Bl[128 * APAD];

    const int tid = threadIdx.x;
    const int wave = tid >> 6, lane = tid & 63;
    const int wr = (wave >> 1) * 64, wc = (wave & 1) * 64;
    const int lrow = lane & 15, lk = (lane >> 4) * 8;

    f32x4 acc[4][4] = {};

    for (int k0 = 0; k0 < CC; k0 += 32) {
#pragma unroll
        for (int i = 0; i < 2; ++i) {
            int idx = tid + 256 * i;
            int r = idx >> 2, ch = idx & 3;
            *(f16x8*)&Ah[r * APAD + ch * 8] =
                *(const f16x8*)&Wh[(size_t)(m0 + r) * CC + k0 + ch * 8];
            *(f16x8*)&Bh[r * APAD + ch * 8] =
                *(const f16x8*)&Xh[(size_t)(n0 + r) * CC + k0 + ch * 8];
            if (which < 2) {
                *(f16x8*)&Al[r * APAD + ch * 8] =
                    *(const f16x8*)&Wl[(size_t)(m0 + r) * CC + k0 + ch * 8];
                *(f16x8*)&Bl[r * APAD + ch * 8] =
                    *(const f16x8*)&Xl[(size_t)(n0 + r) * CC + k0 + ch * 8];
            }
        }
        __syncthreads();
        f16x8 ah[4], al[4], bh[4], bl[4];
#pragma unroll
        for (int i = 0; i < 4; ++i) {
            ah[i] = *(const f16x8*)&Ah[(wr + i * 16 + lrow) * APAD + lk];
            bh[i] = *(const f16x8*)&Bh[(wc + i * 16 + lrow) * APAD + lk];
        }
        if (which < 2) {
#pragma unroll
            for (int i = 0; i < 4; ++i) {
                al[i] = *(const f16x8*)&Al[(wr + i * 16 + lrow) * APAD + lk];
                bl[i] = *(const f16x8*)&Bl[(wc + i * 16 + lrow) * APAD + lk];
            }
        }
#pragma unroll
        for (int i = 0; i < 4; ++i)
#pragma unroll
            for (int j = 0; j < 4; ++j) {
                acc[i][j] = __builtin_amdgcn_mfma_f32_16x16x32_f16(
                    ah[i], bh[j], acc[i][j], 0, 0, 0);
                if (which < 2) {
                    acc[i][j] = __builtin_amdgcn_mfma_f32_16x16x32_f16(
                        ah[i], bl[j], acc[i][j], 0, 0, 0);
                    acc[i][j] = __builtin_amdgcn_mfma_f32_16x16x32_f16(
                        al[i], bh[j], acc[i][j], 0, 0, 0);
                }
            }
        __syncthreads();
    }

    if (which < 2) {
        f16* __restrict__ Oh = ((which == 0) ? Qhi : Khi) + (size_t)b * NN * CC;
#pragma unroll
        for (int i = 0; i < 4; ++i) {
            int cb = m0 + wr + i * 16 + (lane >> 4) * 4;
#pragma unroll
            for (int j = 0; j < 4; ++j) {
                int n = n0 + wc + j * 16 + lrow;
                f16x4 hv;
#pragma unroll
                for (int q = 0; q < 4; ++q) hv[q] = (f16)acc[i][j][q];
                *(f16x4*)&Oh[(size_t)n * CC + cb] = hv;
            }
        }
    } else {
        bf16* __restrict__ Vb = Vb16 + (size_t)b * CC * NN;
#pragma unroll
        for (int i = 0; i < 4; ++i) {
            int cb = m0 + wr + i * 16 + (lane >> 4) * 4;
#pragma unroll
            for (int q = 0; q < 4; ++q) {
                float bvv = bv[cb + q];
#pragma unroll
                for (int j = 0; j < 4; ++j) {
                    int n = n0 + wc + j * 16 + lrow;
                    Vb[(size_t)(cb + q) * NN + n] = __float2bfloat16(acc[i][j][q] + bvv);
                }
            }
        }
    }
}

// ---------------------------------------------------------------------------
// Kernel 2: energy = Qhi . Khi^T -> fp32 logits + per-64-col row-stat
// partials (tile max + expsum) computed in the epilogue (write-bound kernel;
// VALU is free). Partials are per (b, mt=64-col tile, row) — no atomics.
// ---------------------------------------------------------------------------
__global__ __launch_bounds__(256) void energy_mfma_kernel(
    const f16* __restrict__ Qhi, const f16* __restrict__ Khi,
    float* __restrict__ ATT,
    float* __restrict__ rowmax_p, float* __restrict__ rowsum_p)
{
    const int b = blockIdx.z;
    const int n0 = blockIdx.y * 128;
    const int m0 = blockIdx.x * 128;
    const f16* __restrict__ Qh = Qhi + (size_t)b * NN * CC;
    const f16* __restrict__ Kh = Khi + (size_t)b * NN * CC;
    float* __restrict__ Eb = ATT + (size_t)b * NN * NN;

    __shared__ f16 Ah[128 * APAD];
    __shared__ f16 Bh[128 * APAD];

    const int tid = threadIdx.x;
    const int wave = tid >> 6, lane = tid & 63;
    const int wr = (wave >> 1) * 64, wc = (wave & 1) * 64;
    const int lrow = lane & 15, lk = (lane >> 4) * 8;

    f32x4 acc[4][4] = {};

    for (int k0 = 0; k0 < CC; k0 += 32) {
#pragma unroll
        for (int i = 0; i < 2; ++i) {
            int idx = tid + 256 * i;
            int r = idx >> 2, ch = idx & 3;
            *(f16x8*)&Ah[r * APAD + ch * 8] =
                *(const f16x8*)&Qh[(size_t)(n0 + r) * CC + k0 + ch * 8];
            *(f16x8*)&Bh[r * APAD + ch * 8] =
                *(const f16x8*)&Kh[(size_t)(m0 + r) * CC + k0 + ch * 8];
        }
        __syncthreads();
        f16x8 af[4], bf[4];
#pragma unroll
        for (int i = 0; i < 4; ++i) {
            af[i] = *(const f16x8*)&Ah[(wr + i * 16 + lrow) * APAD + lk];
            bf[i] = *(const f16x8*)&Bh[(wc + i * 16 + lrow) * APAD + lk];
        }
#pragma unroll
        for (int i = 0; i < 4; ++i)
#pragma unroll
            for (int j = 0; j < 4; ++j)
                acc[i][j] = __builtin_amdgcn_mfma_f32_16x16x32_f16(
                    af[i], bf[j], acc[i][j], 0, 0, 0);
        __syncthreads();
    }

    // C write
#pragma unroll
    for (int i = 0; i < 4; ++i)
#pragma unroll
        for (int q = 0; q < 4; ++q) {
            int row = n0 + wr + i * 16 + (lane >> 4) * 4 + q;
#pragma unroll
            for (int j = 0; j < 4; ++j) {
                int col = m0 + wc + j * 16 + lrow;
                Eb[(size_t)row * NN + col] = acc[i][j][q];
            }
        }

    // row-stat partials over this wave's 64-col half
    const int mt = (m0 + wc) >> 6;   // 0..31
    float* __restrict__ RMP = rowmax_p + ((size_t)b * 32 + mt) * NN;
    float* __restrict__ RSP = rowsum_p + ((size_t)b * 32 + mt) * NN;
#pragma unroll
    for (int i = 0; i < 4; ++i)
#pragma unroll
        for (int q = 0; q < 4; ++q) {
            float v0 = acc[i][0][q], v1 = acc[i][1][q];
            float v2 = acc[i][2][q], v3 = acc[i][3][q];
            float mx = fmaxf(fmaxf(v0, v1), fmaxf(v2, v3));
#pragma unroll
            for (int d = 1; d < 16; d <<= 1) mx = fmaxf(mx, __shfl_xor(mx, d));
            float es = __expf(v0 - mx) + __expf(v1 - mx)
                     + __expf(v2 - mx) + __expf(v3 - mx);
#pragma unroll
            for (int d = 1; d < 16; d <<= 1) es += __shfl_xor(es, d);
            if (lrow == 0) {
                int row = n0 + wr + i * 16 + (lane >> 4) * 4 + q;
                RMP[row] = mx;
                RSP[row] = es;
            }
        }
}

// ---------------------------------------------------------------------------
// Kernel 2b: merge 32 per-tile row stats -> global row max + 1/denominator.
// ---------------------------------------------------------------------------
__global__ __launch_bounds__(256) void rowmerge_kernel(
    const float* __restrict__ rowmax_p, const float* __restrict__ rowsum_p,
    float* __restrict__ smxG, float* __restrict__ sinvG)
{
    int idx = blockIdx.x * 256 + threadIdx.x;   // b*NN + n
    int b = idx >> 11, n = idx & (NN - 1);
    const float* __restrict__ RM = rowmax_p + (size_t)b * 32 * NN + n;
    const float* __restrict__ RS = rowsum_p + (size_t)b * 32 * NN + n;
    float gmx = -1e30f;
#pragma unroll
    for (int t = 0; t < 32; ++t) gmx = fmaxf(gmx, RM[(size_t)t * NN]);
    float s = 0.f;
#pragma unroll
    for (int t = 0; t < 32; ++t)
        s += RS[(size_t)t * NN] * __expf(RM[(size_t)t * NN] - gmx);
    smxG[idx] = gmx;
    sinvG[idx] = 1.f / s;
}

// ---------------------------------------------------------------------------
// Kernel 3 (fused): softmax convert + column sums + block-transposed bf16
// store. Row stats come precomputed (smxG/sinvG) — E is read ONCE.
// Descending tile order keeps the in-place fp32 clobber safe (r12 proof).
// ---------------------------------------------------------------------------
__global__ __launch_bounds__(1024) void softmax_cs_tr_kernel(
    float* __restrict__ ATT, float* __restrict__ colsum,
    const float* __restrict__ smxG, const float* __restrict__ sinvG)
{
    const int b = blockIdx.y;
    const int n0s = blockIdx.x * 64;
    float* __restrict__ Eb = ATT + (size_t)b * NN * NN;
    bf16* __restrict__ A16 = (bf16*)Eb;

    __shared__ float smx[64], sinv[64];
    __shared__ bf16 T[4][64][72];

    const int tid = threadIdx.x;
    if (tid < 64) {
        smx[tid]  = smxG[b * NN + n0s + tid];
        sinv[tid] = sinvG[b * NN + n0s + tid];
    }
    __syncthreads();

    const int g = tid >> 8, t = tid & 255;
    for (int rd = 0; rd < 8; ++rd) {
        const int mt = 28 - 4 * rd + g;
        const int m0 = mt * 64;
#pragma unroll
        for (int i = 0; i < 4; ++i) {
            int idx = t + 256 * i;
            int nl = idx >> 4, mc = (idx & 15) * 4;
            float4 v = *(const float4*)&Eb[(size_t)(n0s + nl) * NN + m0 + mc];
            float mx = smx[nl], iv = sinv[nl];
            T[g][mc + 0][nl] = __float2bfloat16(__expf(v.x - mx) * iv);
            T[g][mc + 1][nl] = __float2bfloat16(__expf(v.y - mx) * iv);
            T[g][mc + 2][nl] = __float2bfloat16(__expf(v.z - mx) * iv);
            T[g][mc + 3][nl] = __float2bfloat16(__expf(v.w - mx) * iv);
        }
        __syncthreads();
        {
            int ml = t >> 2, q = t & 3;
            float cs = 0.f;
#pragma unroll
            for (int j = 0; j < 16; ++j)
                cs += __bfloat162float(T[g][ml][q * 16 + j]);
            cs += __shfl_xor(cs, 1);
            cs += __shfl_xor(cs, 2);
            if (q == 0) atomicAdd(&colsum[b * NN + m0 + ml], cs);
        }
#pragma unroll
        for (int i = 0; i < 2; ++i) {
            int idx = t + 256 * i;
            int mr = idx >> 3, ch = idx & 7;
            u16x8 w = *(const u16x8*)&T[g][mr][ch * 8];
            *(u16x8*)&A16[(size_t)(n0s + mr) * (2 * NN) + NN + m0 + ch * 8] = w;
        }
        __syncthreads();
    }
}

// ---------------------------------------------------------------------------
// Kernel 5: x_r_raw = V . A^T (bf16 MFMA, 64x64 tile, BK=64) from the
// block-transposed layout; rcv applied in the epilogue; writes Dt16[n][c].
// ---------------------------------------------------------------------------
__global__ __launch_bounds__(256) void xr_mfma_kernel(
    const bf16* __restrict__ Vb16, const float* __restrict__ ATT,
    const float* __restrict__ colsum, const float* __restrict__ x,
    f16* __restrict__ Dt16)
{
    const int b  = blockIdx.z;
    const int c0 = blockIdx.y * 64;
    const int n0 = blockIdx.x * 64;
    const bf16* __restrict__ Vb = Vb16 + (size_t)b * CC * NN;
    const bf16* __restrict__ A16 = (const bf16*)(ATT + (size_t)b * NN * NN);
    const float* __restrict__ Xb = x + (size_t)b * CC * NN;
    f16* __restrict__ Db = Dt16 + (size_t)b * NN * CC;

    __shared__ bf16 Asl[64 * XPAD];
    __shared__ bf16 Bsl[64 * XPAD];
    __shared__ float rcvL[64];

    const int tid = threadIdx.x;
    if (tid < 64) rcvL[tid] = 1.f / (1e-9f + colsum[b * NN + n0 + tid]);

    const int wave = tid >> 6, lane = tid & 63;
    const int wr = (wave >> 1) * 32, wc = (wave & 1) * 32;
    const int lrow = lane & 15, lk = (lane >> 4) * 8;

    f32x4 acc[2][2] = {};

    for (int k0 = 0; k0 < NN; k0 += 64) {
#pragma unroll
        for (int i = 0; i < 2; ++i) {
            int idx = tid + 256 * i;
            int r = idx >> 3, ch = idx & 7;
            *(u16x8*)&Asl[r * XPAD + ch * 8] =
                *(const u16x8*)&Vb[(size_t)(c0 + r) * NN + k0 + ch * 8];
            *(u16x8*)&Bsl[r * XPAD + ch * 8] =
                *(const u16x8*)&A16[(size_t)(k0 + r) * (2 * NN) + NN + n0 + ch * 8];
        }
        __syncthreads();
#pragma unroll
        for (int ks = 0; ks < 2; ++ks) {
            s16x8 af[2], bf[2];
#pragma unroll
            for (int i = 0; i < 2; ++i) {
                af[i] = *(const s16x8*)&Asl[(wr + i * 16 + lrow) * XPAD + ks * 32 + lk];
                bf[i] = *(const s16x8*)&Bsl[(wc + i * 16 + lrow) * XPAD + ks * 32 + lk];
            }
#pragma unroll
            for (int i = 0; i < 2; ++i)
#pragma unroll
                for (int j = 0; j < 2; ++j)
                    acc[i][j] = __builtin_amdgcn_mfma_f32_16x16x32_bf16(
                        af[i], bf[j], acc[i][j], 0, 0, 0);
        }
        __syncthreads();
    }

#pragma unroll
    for (int i = 0; i < 2; ++i) {
        int cb = c0 + wr + i * 16 + (lane >> 4) * 4;
#pragma unroll
        for (int j = 0; j < 2; ++j) {
            int ln = wc + j * 16 + lrow;
            int n = n0 + ln;
            float rc = rcvL[ln];
            f16x4 dv;
#pragma unroll
            for (int q = 0; q < 4; ++q)
                dv[q] = (f16)(Xb[(size_t)(cb + q) * NN + n] - acc[i][j][q] * rc);
            *(f16x4*)&Db[(size_t)n * CC + cb] = dv;
        }
    }
}

// ---------------------------------------------------------------------------
// Kernel 6: XZ(bf16) = alpha*(Wt*Dt16 + bt) + beta; BN sums from fp32 values.
// ---------------------------------------------------------------------------
__global__ __launch_bounds__(256) void xz_mfma_kernel(
    const f16* __restrict__ Whi, const f16* __restrict__ Dt16,
    const float* __restrict__ bt, const float* __restrict__ alpha,
    const float* __restrict__ beta, bf16* __restrict__ XZ,
    float* __restrict__ bnsum, float* __restrict__ bnsumsq)
{
    const int b = blockIdx.z;
    const int m0 = blockIdx.y * 128;
    const int n0 = blockIdx.x * 128;
    const f16* __restrict__ Wb = Whi + (size_t)3 * CC * CC;   // Wt (hi)
    const f16* __restrict__ Db = Dt16 + (size_t)b * NN * CC;
    bf16* __restrict__ Zb = XZ + (size_t)b * CC * NN;

    __shared__ f16 Asl[128 * APAD];
    __shared__ f16 Bsl[128 * APAD];

    const int tid = threadIdx.x;
    const int wave = tid >> 6, lane = tid & 63;
    const int wr = (wave >> 1) * 64, wc = (wave & 1) * 64;
    const int lrow = lane & 15, lk = (lane >> 4) * 8;

    f32x4 acc[4][4] = {};

    for (int k0 = 0; k0 < CC; k0 += 32) {
#pragma unroll
        for (int i = 0; i < 2; ++i) {
            int idx = tid + 256 * i;
            int r = idx >> 2, ch = idx & 3;
            *(f16x8*)&Asl[r * APAD + ch * 8] =
                *(const f16x8*)&Wb[(size_t)(m0 + r) * CC + k0 + ch * 8];
            *(f16x8*)&Bsl[r * APAD + ch * 8] =
                *(const f16x8*)&Db[(size_t)(n0 + r) * CC + k0 + ch * 8];
        }
        __syncthreads();
        f16x8 af[4], bf[4];
#pragma unroll
        for (int i = 0; i < 4; ++i) {
            af[i] = *(const f16x8*)&Asl[(wr + i * 16 + lrow) * APAD + lk];
            bf[i] = *(const f16x8*)&Bsl[(wc + i * 16 + lrow) * APAD + lk];
        }
#pragma unroll
        for (int i = 0; i < 4; ++i)
#pragma unroll
            for (int j = 0; j < 4; ++j)
                acc[i][j] = __builtin_amdgcn_mfma_f32_16x16x32_f16(
                    af[i], bf[j], acc[i][j], 0, 0, 0);
        __syncthreads();
    }

#pragma unroll
    for (int i = 0; i < 4; ++i) {
#pragma unroll
        for (int q = 0; q < 4; ++q) {
            int o = m0 + wr + i * 16 + (lane >> 4) * 4 + q;
            float al = alpha[o], be = beta[o], bb = bt[o];
            float s1 = 0.f, s2 = 0.f;
#pragma unroll
            for (int j = 0; j < 4; ++j) {
                int n = n0 + wc + j * 16 + lrow;
                float z = al * (acc[i][j][q] + bb) + be;
                Zb[(size_t)o * NN + n] = __float2bfloat16(z);
                s1 += z; s2 += z * z;
            }
#pragma unroll
            for (int d = 1; d < 16; d <<= 1) {
                s1 += __shfl_xor(s1, d);
                s2 += __shfl_xor(s2, d);
            }
            if (lrow == 0) {
                atomicAdd(&bnsum[o], s1);
                atomicAdd(&bnsumsq[o], s2);
            }
        }
    }
}

// ---------------------------------------------------------------------------
// Kernel 7: out = x + relu(gamma*(XZ-mean)*rsqrt(var+eps)+beta)
// ---------------------------------------------------------------------------
__global__ __launch_bounds__(256) void final_kernel(
    const float* __restrict__ x, const bf16* __restrict__ XZ,
    const float* __restrict__ bnsum, const float* __restrict__ bnsumsq,
    const float* __restrict__ gamma, const float* __restrict__ bbeta,
    float* __restrict__ out)
{
    const int i4 = blockIdx.x * 256 + threadIdx.x;
    const int elem = i4 * 4;
    const int c = (elem / NN) % CC;
    const float inv_cnt = 1.f / (float)(BB * NN);
    const float mean = bnsum[c] * inv_cnt;
    const float var  = bnsumsq[c] * inv_cnt - mean * mean;
    const float rs = rsqrtf(var + BN_EPS);
    const float g = gamma[c], bb = bbeta[c];

    ushort4 zu = *(const ushort4*)&XZ[elem];
    float4 xv = *(const float4*)&x[elem];
    float z0 = __uint_as_float((unsigned)zu.x << 16);
    float z1 = __uint_as_float((unsigned)zu.y << 16);
    float z2 = __uint_as_float((unsigned)zu.z << 16);
    float z3 = __uint_as_float((unsigned)zu.w << 16);
    float4 o;
    o.x = xv.x + fmaxf(g * (z0 - mean) * rs + bb, 0.f);
    o.y = xv.y + fmaxf(g * (z1 - mean) * rs + bb, 0.f);
    o.z = xv.z + fmaxf(g * (z2 - mean) * rs + bb, 0.f);
    o.w = xv.w + fmaxf(g * (z3 - mean) * rs + bb, 0.f);
    *(float4*)&out[elem] = o;
}

// ---------------------------------------------------------------------------

extern "C" void kernel_launch(void* const* d_in, const int* in_sizes, int n_in,
                              void* d_out, int out_size, void* d_ws, size_t ws_size,
                              hipStream_t stream) {
    const float* x     = (const float*)d_in[0];
    const float* Wq    = (const float*)d_in[1];
    const float* Wk    = (const float*)d_in[2];
    const float* Wv    = (const float*)d_in[3];
    const float* bv    = (const float*)d_in[4];
    const float* Wt    = (const float*)d_in[5];
    const float* bt    = (const float*)d_in[6];
    const float* gamma = (const float*)d_in[7];
    const float* bbeta = (const float*)d_in[8];
    const float* alpha = (const float*)d_in[9];
    const float* beta  = (const float*)d_in[10];
    float* out = (float*)d_out;

    const size_t BCN = (size_t)BB * CC * NN;   // 4,194,304 elements
    const size_t WSZ = (size_t)4 * CC * CC;    // 262,144

    f16* Whi = (f16*)d_ws;                     // 4 x [C][C] hi
    f16* Wlo = Whi + WSZ;                      // 4 x [C][C] lo
    bf16* Vb16 = (bf16*)(Wlo + WSZ);           // [B][C][N] bf16
    f16* Qhi = (f16*)(Vb16 + BCN);             // [B][N][C]
    f16* Khi = Qhi + BCN;                      // [B][N][C]
    float* ATT = (float*)(Khi + BCN);          // [B][N][N]: fp32 logits, bf16 A^T in second halves
    bf16* XZ = (bf16*)(ATT + (size_t)BB * NN * NN);  // [B][C][N] bf16
    float* colsum  = (float*)(XZ + BCN);       // [B][N]
    float* bnsum   = colsum + (size_t)BB * NN; // [C]
    float* bnsumsq = bnsum + CC;               // [C]
    float* rowmax_p = bnsumsq + CC;            // [B][32][N] fp32
    float* rowsum_p = rowmax_p + (size_t)BB * 32 * NN;
    float* smxG     = rowsum_p + (size_t)BB * 32 * NN;   // [B][N]
    float* sinvG    = smxG + (size_t)BB * NN;            // [B][N]

    // Dt16 overlays Qhi (dead after energy). Xhi/Xlo overlay batch-0 ATT.
    f16* Dt16 = Qhi;
    f16* Xhi = (f16*)ATT;                      // [B][N][C]
    f16* Xlo = Xhi + BCN;                      // [B][N][C]

    hipMemsetAsync(colsum, 0, (size_t)(BB * NN + 2 * CC) * sizeof(float), stream);

    prep_w_kernel<<<dim3(4 * CC * CC / 2048), 256, 0, stream>>>(
        Wq, Wk, Wv, Wt, Whi, Wlo);
    prep_x_kernel<<<dim3(NN / 64, CC / 64, BB), 256, 0, stream>>>(x, Xhi, Xlo);
    proj_mfma_kernel<<<dim3(NN / 128, CC / 128, 3 * BB), 256, 0, stream>>>(
        Whi, Wlo, Xhi, Xlo, bv, Qhi, Khi, Vb16);
    energy_mfma_kernel<<<dim3(NN / 128, NN / 128, BB), 256, 0, stream>>>(
        Qhi, Khi, ATT, rowmax_p, rowsum_p);
    rowmerge_kernel<<<dim3(BB * NN / 256), 256, 0, stream>>>(
        rowmax_p, rowsum_p, smxG, sinvG);
    softmax_cs_tr_kernel<<<dim3(NN / 64, BB), 1024, 0, stream>>>(
        ATT, colsum, smxG, sinvG);
    xr_mfma_kernel<<<dim3(NN / 64, CC / 64, BB), 256, 0, stream>>>(
        Vb16, ATT, colsum, x, Dt16);
    xz_mfma_kernel<<<dim3(NN / 128, CC / 128, BB), 256, 0, stream>>>(
        Whi, Dt16, bt, alpha, beta, XZ, bnsum, bnsumsq);
    final_kernel<<<dim3((int)(BCN / 4 / 256)), 256, 0, stream>>>(
        x, XZ, bnsum, bnsumsq, gamma, bbeta, out);
}

// Round 15
// 231.375 us; speedup vs baseline: 1.1123x; 1.0585x over previous
//
#include <hip/hip_runtime.h>
#include <hip/hip_bf16.h>
#include <math.h>

#define BB 8
#define CC 256
#define NN 2048
static constexpr float BN_EPS = 1e-5f;

typedef _Float16 f16;
typedef f16 f16x4 __attribute__((ext_vector_type(4)));
typedef f16 f16x8 __attribute__((ext_vector_type(8)));
typedef float f32x4 __attribute__((ext_vector_type(4)));
typedef short s16x8 __attribute__((ext_vector_type(8)));     // 8 bf16 (MFMA operand)
typedef unsigned short u16x8 __attribute__((ext_vector_type(8)));  // 16B raw
typedef __hip_bfloat16 bf16;

#define APAD 40   // 16-bit-elem row stride (32 data + 8 pad) = 80B, 16B-aligned
#define XPAD 72   // 16-bit-elem row stride (64 data + 8 pad) = 144B, 16B-aligned

__device__ inline float bf2f(unsigned short u) {
    return __uint_as_float((unsigned)u << 16);
}

// ---------------------------------------------------------------------------
// Prep A: four C x C weight matrices -> hi/lo f16 planes (concatenated).
// ---------------------------------------------------------------------------
__global__ __launch_bounds__(256) void prep_w_kernel(
    const float* __restrict__ Wq, const float* __restrict__ Wk,
    const float* __restrict__ Wv, const float* __restrict__ Wt,
    f16* __restrict__ Whi, f16* __restrict__ Wlo)
{
    int idx = (blockIdx.x * 256 + threadIdx.x) * 8;   // over 4*C*C
    const float* s = (idx < 65536) ? Wq : (idx < 131072) ? Wk
                    : (idx < 196608) ? Wv : Wt;
    int off = idx & 65535;
    float4 a = *(const float4*)&s[off];
    float4 b = *(const float4*)&s[off + 4];
    float v[8] = {a.x, a.y, a.z, a.w, b.x, b.y, b.z, b.w};
    f16x8 h, l;
#pragma unroll
    for (int j = 0; j < 8; ++j) {
        f16 hh = (f16)v[j];
        f16 ll = (f16)(v[j] - (float)hh);
        h[j] = hh;
        l[j] = ll;
    }
    *(f16x8*)&Whi[idx] = h;
    *(f16x8*)&Wlo[idx] = l;
}

// ---------------------------------------------------------------------------
// Prep B: Xhi/Xlo[b][n][c] = split (f16) of x[b][c][n]  (LDS-tiled transpose)
// ---------------------------------------------------------------------------
__global__ __launch_bounds__(256) void prep_x_kernel(
    const float* __restrict__ x, f16* __restrict__ Xhi, f16* __restrict__ Xlo)
{
    const int b = blockIdx.z, c0 = blockIdx.y * 64, n0 = blockIdx.x * 64;
    const float* __restrict__ Xb = x + (size_t)b * CC * NN;
    f16* __restrict__ Oh = Xhi + (size_t)b * NN * CC;
    f16* __restrict__ Ol = Xlo + (size_t)b * NN * CC;
    __shared__ f16 Th[64][72];
    __shared__ f16 Tl[64][72];
    const int tid = threadIdx.x;
    const int r = tid >> 4, c4 = (tid & 15) * 4;
#pragma unroll
    for (int i = 0; i < 4; ++i) {
        int rr = r + i * 16;
        float4 v = *(const float4*)&Xb[(size_t)(c0 + rr) * NN + n0 + c4];
        float vv[4] = {v.x, v.y, v.z, v.w};
#pragma unroll
        for (int j = 0; j < 4; ++j) {
            f16 hh = (f16)vv[j];
            f16 ll = (f16)(vv[j] - (float)hh);
            Th[c4 + j][rr] = hh;
            Tl[c4 + j][rr] = ll;
        }
    }
    __syncthreads();
#pragma unroll
    for (int i = 0; i < 2; ++i) {
        int idx = tid + 256 * i;
        int n = idx >> 3, cg = (idx & 7) * 8;
        *(f16x8*)&Oh[(size_t)(n0 + n) * CC + c0 + cg] = *(f16x8*)&Th[n][cg];
        *(f16x8*)&Ol[(size_t)(n0 + n) * CC + c0 + cg] = *(f16x8*)&Tl[n][cg];
    }
}

// ---------------------------------------------------------------------------
// Kernel 1: projections. Q/K: split-precision (hi*hi + hi*lo + lo*hi) ->
// f16 [b][n][c]. V: hi-only -> bf16 [b][c][n] (+bv).
// ---------------------------------------------------------------------------
__global__ __launch_bounds__(256) void proj_mfma_kernel(
    const f16* __restrict__ Whi, const f16* __restrict__ Wlo,
    const f16* __restrict__ Xhi, const f16* __restrict__ Xlo,
    const float* __restrict__ bv,
    f16* __restrict__ Qhi, f16* __restrict__ Khi, bf16* __restrict__ Vb16)
{
    const int which = blockIdx.z >> 3;
    const int b     = blockIdx.z & 7;
    const f16* __restrict__ Wh = Whi + (size_t)which * CC * CC;
    const f16* __restrict__ Wl = Wlo + (size_t)which * CC * CC;
    const f16* __restrict__ Xh = Xhi + (size_t)b * NN * CC;
    const f16* __restrict__ Xl = Xlo + (size_t)b * NN * CC;

    const int m0 = blockIdx.y * 128;   // output channels
    const int n0 = blockIdx.x * 128;   // points

    __shared__ f16 Ah[128 * APAD];
    __shared__ f16 Al[128 * APAD];
    __shared__ f16 Bh[128 * APAD];
    __shared__ f16 Bl[128 * APAD];

    const int tid = threadIdx.x;
    const int wave = tid >> 6, lane = tid & 63;
    const int wr = (wave >> 1) * 64, wc = (wave & 1) * 64;
    const int lrow = lane & 15, lk = (lane >> 4) * 8;

    f32x4 acc[4][4] = {};

    for (int k0 = 0; k0 < CC; k0 += 32) {
#pragma unroll
        for (int i = 0; i < 2; ++i) {
            int idx = tid + 256 * i;
            int r = idx >> 2, ch = idx & 3;
            *(f16x8*)&Ah[r * APAD + ch * 8] =
                *(const f16x8*)&Wh[(size_t)(m0 + r) * CC + k0 + ch * 8];
            *(f16x8*)&Bh[r * APAD + ch * 8] =
                *(const f16x8*)&Xh[(size_t)(n0 + r) * CC + k0 + ch * 8];
            if (which < 2) {
                *(f16x8*)&Al[r * APAD + ch * 8] =
                    *(const f16x8*)&Wl[(size_t)(m0 + r) * CC + k0 + ch * 8];
                *(f16x8*)&Bl[r * APAD + ch * 8] =
                    *(const f16x8*)&Xl[(size_t)(n0 + r) * CC + k0 + ch * 8];
            }
        }
        __syncthreads();
        f16x8 ah[4], al[4], bh[4], bl[4];
#pragma unroll
        for (int i = 0; i < 4; ++i) {
            ah[i] = *(const f16x8*)&Ah[(wr + i * 16 + lrow) * APAD + lk];
            bh[i] = *(const f16x8*)&Bh[(wc + i * 16 + lrow) * APAD + lk];
        }
        if (which < 2) {
#pragma unroll
            for (int i = 0; i < 4; ++i) {
                al[i] = *(const f16x8*)&Al[(wr + i * 16 + lrow) * APAD + lk];
                bl[i] = *(const f16x8*)&Bl[(wc + i * 16 + lrow) * APAD + lk];
            }
        }
#pragma unroll
        for (int i = 0; i < 4; ++i)
#pragma unroll
            for (int j = 0; j < 4; ++j) {
                acc[i][j] = __builtin_amdgcn_mfma_f32_16x16x32_f16(
                    ah[i], bh[j], acc[i][j], 0, 0, 0);
                if (which < 2) {
                    acc[i][j] = __builtin_amdgcn_mfma_f32_16x16x32_f16(
                        ah[i], bl[j], acc[i][j], 0, 0, 0);
                    acc[i][j] = __builtin_amdgcn_mfma_f32_16x16x32_f16(
                        al[i], bh[j], acc[i][j], 0, 0, 0);
                }
            }
        __syncthreads();
    }

    if (which < 2) {
        f16* __restrict__ Oh = ((which == 0) ? Qhi : Khi) + (size_t)b * NN * CC;
#pragma unroll
        for (int i = 0; i < 4; ++i) {
            int cb = m0 + wr + i * 16 + (lane >> 4) * 4;
#pragma unroll
            for (int j = 0; j < 4; ++j) {
                int n = n0 + wc + j * 16 + lrow;
                f16x4 hv;
#pragma unroll
                for (int q = 0; q < 4; ++q) hv[q] = (f16)acc[i][j][q];
                *(f16x4*)&Oh[(size_t)n * CC + cb] = hv;
            }
        }
    } else {
        bf16* __restrict__ Vb = Vb16 + (size_t)b * CC * NN;
#pragma unroll
        for (int i = 0; i < 4; ++i) {
            int cb = m0 + wr + i * 16 + (lane >> 4) * 4;
#pragma unroll
            for (int q = 0; q < 4; ++q) {
                float bvv = bv[cb + q];
#pragma unroll
                for (int j = 0; j < 4; ++j) {
                    int n = n0 + wc + j * 16 + lrow;
                    Vb[(size_t)(cb + q) * NN + n] = __float2bfloat16(acc[i][j][q] + bvv);
                }
            }
        }
    }
}

// ---------------------------------------------------------------------------
// Kernel 2: energy + per-tile softmax: computes E = Q.K^T, per-(row, 64-col
// tile) max m_t and expsum s_t, and stores P^T[b][m][n] = bf16(exp(E - m_t))
// TRANSPOSED via an LDS tile (coalesced 256B runs). fp32 E never hits HBM.
// ---------------------------------------------------------------------------
__global__ __launch_bounds__(256) void energy_mfma_kernel(
    const f16* __restrict__ Qhi, const f16* __restrict__ Khi,
    bf16* __restrict__ AT16,
    float* __restrict__ rowmax_p, float* __restrict__ rowsum_p)
{
    const int b = blockIdx.z;
    const int n0 = blockIdx.y * 128;
    const int m0 = blockIdx.x * 128;
    const f16* __restrict__ Qh = Qhi + (size_t)b * NN * CC;
    const f16* __restrict__ Kh = Khi + (size_t)b * NN * CC;

    __shared__ f16 Ah[128 * APAD];
    __shared__ f16 Bh[128 * APAD];
    __shared__ bf16 Tt[64 * 136];   // transpose staging: [m-local][n-local]

    const int tid = threadIdx.x;
    const int wave = tid >> 6, lane = tid & 63;
    const int wr = (wave >> 1) * 64, wc = (wave & 1) * 64;
    const int lrow = lane & 15, lk = (lane >> 4) * 8;

    f32x4 acc[4][4] = {};

    for (int k0 = 0; k0 < CC; k0 += 32) {
#pragma unroll
        for (int i = 0; i < 2; ++i) {
            int idx = tid + 256 * i;
            int r = idx >> 2, ch = idx & 3;
            *(f16x8*)&Ah[r * APAD + ch * 8] =
                *(const f16x8*)&Qh[(size_t)(n0 + r) * CC + k0 + ch * 8];
            *(f16x8*)&Bh[r * APAD + ch * 8] =
                *(const f16x8*)&Kh[(size_t)(m0 + r) * CC + k0 + ch * 8];
        }
        __syncthreads();
        f16x8 af[4], bf[4];
#pragma unroll
        for (int i = 0; i < 4; ++i) {
            af[i] = *(const f16x8*)&Ah[(wr + i * 16 + lrow) * APAD + lk];
            bf[i] = *(const f16x8*)&Bh[(wc + i * 16 + lrow) * APAD + lk];
        }
#pragma unroll
        for (int i = 0; i < 4; ++i)
#pragma unroll
            for (int j = 0; j < 4; ++j)
                acc[i][j] = __builtin_amdgcn_mfma_f32_16x16x32_f16(
                    af[i], bf[j], acc[i][j], 0, 0, 0);
        __syncthreads();
    }

    // stats: overwrite acc with p = exp(v - tile-max); store m_t, s_t
    const int mt_w = (m0 + wc) >> 6;   // this wave's 64-col tile index
    float* __restrict__ RMP = rowmax_p + ((size_t)b * 32 + mt_w) * NN;
    float* __restrict__ RSP = rowsum_p + ((size_t)b * 32 + mt_w) * NN;
#pragma unroll
    for (int i = 0; i < 4; ++i)
#pragma unroll
        for (int q = 0; q < 4; ++q) {
            float v0 = acc[i][0][q], v1 = acc[i][1][q];
            float v2 = acc[i][2][q], v3 = acc[i][3][q];
            float mx = fmaxf(fmaxf(v0, v1), fmaxf(v2, v3));
#pragma unroll
            for (int d = 1; d < 16; d <<= 1) mx = fmaxf(mx, __shfl_xor(mx, d));
            float p0 = __expf(v0 - mx), p1 = __expf(v1 - mx);
            float p2 = __expf(v2 - mx), p3 = __expf(v3 - mx);
            acc[i][0][q] = p0; acc[i][1][q] = p1;
            acc[i][2][q] = p2; acc[i][3][q] = p3;
            float es = p0 + p1 + p2 + p3;
#pragma unroll
            for (int d = 1; d < 16; d <<= 1) es += __shfl_xor(es, d);
            if (lrow == 0) {
                int row = n0 + wr + i * 16 + (lane >> 4) * 4 + q;
                RMP[row] = mx;
                RSP[row] = es;
            }
        }

    // transposed bf16 store via LDS, two 64-col chunks
    bf16* __restrict__ Ab = AT16 + (size_t)b * NN * NN;   // [m][n]
    for (int chunk = 0; chunk < 2; ++chunk) {
        if ((wave & 1) == chunk) {
#pragma unroll
            for (int i = 0; i < 4; ++i)
#pragma unroll
                for (int j = 0; j < 4; ++j)
#pragma unroll
                    for (int q = 0; q < 4; ++q)
                        Tt[(j * 16 + lrow) * 136 + wr + i * 16 + (lane >> 4) * 4 + q] =
                            __float2bfloat16(acc[i][j][q]);
        }
        __syncthreads();
#pragma unroll
        for (int u = 0; u < 4; ++u) {
            int e = tid + u * 256;              // 0..1023
            int mrow = e >> 4, nch = (e & 15) * 8;
            *(u16x8*)&Ab[(size_t)(m0 + chunk * 64 + mrow) * NN + n0 + nch] =
                *(const u16x8*)&Tt[mrow * 136 + nch];
        }
        __syncthreads();
    }
}

// ---------------------------------------------------------------------------
// Kernel 2b: merge 32 per-tile row stats -> global row max + 1/denominator.
// ---------------------------------------------------------------------------
__global__ __launch_bounds__(256) void rowmerge_kernel(
    const float* __restrict__ rowmax_p, const float* __restrict__ rowsum_p,
    float* __restrict__ smxG, float* __restrict__ sinvG)
{
    int idx = blockIdx.x * 256 + threadIdx.x;   // b*NN + n
    int b = idx >> 11, n = idx & (NN - 1);
    const float* __restrict__ RM = rowmax_p + (size_t)b * 32 * NN + n;
    const float* __restrict__ RS = rowsum_p + (size_t)b * 32 * NN + n;
    float gmx = -1e30f;
#pragma unroll
    for (int t = 0; t < 32; ++t) gmx = fmaxf(gmx, RM[(size_t)t * NN]);
    float s = 0.f;
#pragma unroll
    for (int t = 0; t < 32; ++t)
        s += RS[(size_t)t * NN] * __expf(RM[(size_t)t * NN] - gmx);
    smxG[idx] = gmx;
    sinvG[idx] = 1.f / s;
}

// ---------------------------------------------------------------------------
// Kernel 4: colsum[m] = sum_n P^T[m][n] * fvec(n, mt(m)), with
// fvec(n,mt) = exp(m_t(n,mt) - gmx(n)) * sinv(n) held in registers.
// One block per (mt, b); block owns rows m = mt*64..+63 -> no atomics.
// ---------------------------------------------------------------------------
__global__ __launch_bounds__(256) void colsum_fvec_kernel(
    const bf16* __restrict__ AT16, const float* __restrict__ rowmax_p,
    const float* __restrict__ smxG, const float* __restrict__ sinvG,
    float* __restrict__ colsum)
{
    const int mt = blockIdx.x, b = blockIdx.y;
    const bf16* __restrict__ Ab = AT16 + (size_t)b * NN * NN;
    const float* __restrict__ RMP = rowmax_p + ((size_t)b * 32 + mt) * NN;
    const int tid = threadIdx.x;
    const int wave = tid >> 6, lane = tid & 63;

    // per-lane fvec registers for its 32 n-slots (k = p*512 + lane*8 + e)
    float fv[4][8];
#pragma unroll
    for (int p = 0; p < 4; ++p) {
        int k = p * 512 + lane * 8;
        float4 m0v = *(const float4*)&RMP[k];
        float4 m1v = *(const float4*)&RMP[k + 4];
        float4 g0 = *(const float4*)&smxG[b * NN + k];
        float4 g1 = *(const float4*)&smxG[b * NN + k + 4];
        float4 s0 = *(const float4*)&sinvG[b * NN + k];
        float4 s1 = *(const float4*)&sinvG[b * NN + k + 4];
        fv[p][0] = __expf(m0v.x - g0.x) * s0.x;
        fv[p][1] = __expf(m0v.y - g0.y) * s0.y;
        fv[p][2] = __expf(m0v.z - g0.z) * s0.z;
        fv[p][3] = __expf(m0v.w - g0.w) * s0.w;
        fv[p][4] = __expf(m1v.x - g1.x) * s1.x;
        fv[p][5] = __expf(m1v.y - g1.y) * s1.y;
        fv[p][6] = __expf(m1v.z - g1.z) * s1.z;
        fv[p][7] = __expf(m1v.w - g1.w) * s1.w;
    }

#pragma unroll
    for (int rr = 0; rr < 16; ++rr) {
        int m = mt * 64 + wave * 16 + rr;
        const bf16* __restrict__ R = &Ab[(size_t)m * NN];
        float cs = 0.f;
#pragma unroll
        for (int p = 0; p < 4; ++p) {
            int k = p * 512 + lane * 8;
            u16x8 v = *(const u16x8*)&R[k];
#pragma unroll
            for (int e = 0; e < 8; ++e)
                cs += bf2f((unsigned short)v[e]) * fv[p][e];
        }
#pragma unroll
        for (int d = 1; d < 64; d <<= 1) cs += __shfl_xor(cs, d);
        if (lane == 0) colsum[b * NN + m] = cs;
    }
}

// ---------------------------------------------------------------------------
// Kernel 5: x_r_raw = V . A^T. B-staging reads P^T and folds the fvec
// rescale (fp32) during staging; rcv applied in epilogue; Dt16[n][c] out.
// ---------------------------------------------------------------------------
__global__ __launch_bounds__(256) void xr_mfma_kernel(
    const bf16* __restrict__ Vb16, const bf16* __restrict__ AT16,
    const float* __restrict__ rowmax_p, const float* __restrict__ smxG,
    const float* __restrict__ sinvG, const float* __restrict__ colsum,
    const float* __restrict__ x, f16* __restrict__ Dt16)
{
    const int b  = blockIdx.z;
    const int c0 = blockIdx.y * 64;
    const int n0 = blockIdx.x * 64;   // output point tile (single mt)
    const bf16* __restrict__ Vb = Vb16 + (size_t)b * CC * NN;
    const bf16* __restrict__ Ab = AT16 + (size_t)b * NN * NN;
    const float* __restrict__ Xb = x + (size_t)b * CC * NN;
    f16* __restrict__ Db = Dt16 + (size_t)b * NN * CC;

    __shared__ bf16 Asl[64 * XPAD];
    __shared__ bf16 Bsl[64 * XPAD];
    __shared__ float fvecL[NN];
    __shared__ float rcvL[64];

    const int tid = threadIdx.x;
    const int mt = n0 >> 6;
    const float* __restrict__ RMP = rowmax_p + ((size_t)b * 32 + mt) * NN;
    for (int k = tid; k < NN; k += 256)
        fvecL[k] = __expf(RMP[k] - smxG[b * NN + k]) * sinvG[b * NN + k];
    if (tid < 64) rcvL[tid] = 1.f / (1e-9f + colsum[b * NN + n0 + tid]);
    __syncthreads();

    const int wave = tid >> 6, lane = tid & 63;
    const int wr = (wave >> 1) * 32, wc = (wave & 1) * 32;
    const int lrow = lane & 15, lk = (lane >> 4) * 8;

    f32x4 acc[2][2] = {};

    for (int k0 = 0; k0 < NN; k0 += 64) {
#pragma unroll
        for (int i = 0; i < 2; ++i) {
            int idx = tid + 256 * i;
            int r = idx >> 3, ch = idx & 7;
            *(u16x8*)&Asl[r * XPAD + ch * 8] =
                *(const u16x8*)&Vb[(size_t)(c0 + r) * NN + k0 + ch * 8];
            u16x8 v = *(const u16x8*)&Ab[(size_t)(n0 + r) * NN + k0 + ch * 8];
            bf16 w[8];
#pragma unroll
            for (int e = 0; e < 8; ++e)
                w[e] = __float2bfloat16(
                    bf2f((unsigned short)v[e]) * fvecL[k0 + ch * 8 + e]);
            *(u16x8*)&Bsl[r * XPAD + ch * 8] = *(const u16x8*)w;
        }
        __syncthreads();
#pragma unroll
        for (int ks = 0; ks < 2; ++ks) {
            s16x8 af[2], bf[2];
#pragma unroll
            for (int i = 0; i < 2; ++i) {
                af[i] = *(const s16x8*)&Asl[(wr + i * 16 + lrow) * XPAD + ks * 32 + lk];
                bf[i] = *(const s16x8*)&Bsl[(wc + i * 16 + lrow) * XPAD + ks * 32 + lk];
            }
#pragma unroll
            for (int i = 0; i < 2; ++i)
#pragma unroll
                for (int j = 0; j < 2; ++j)
                    acc[i][j] = __builtin_amdgcn_mfma_f32_16x16x32_bf16(
                        af[i], bf[j], acc[i][j], 0, 0, 0);
        }
        __syncthreads();
    }

#pragma unroll
    for (int i = 0; i < 2; ++i) {
        int cb = c0 + wr + i * 16 + (lane >> 4) * 4;
#pragma unroll
        for (int j = 0; j < 2; ++j) {
            int ln = wc + j * 16 + lrow;
            int n = n0 + ln;
            float rc = rcvL[ln];
            f16x4 dv;
#pragma unroll
            for (int q = 0; q < 4; ++q)
                dv[q] = (f16)(Xb[(size_t)(cb + q) * NN + n] - acc[i][j][q] * rc);
            *(f16x4*)&Db[(size_t)n * CC + cb] = dv;
        }
    }
}

// ---------------------------------------------------------------------------
// Kernel 6: XZ(bf16) = alpha*(Wt*Dt16 + bt) + beta; BN sums from fp32 values.
// ---------------------------------------------------------------------------
__global__ __launch_bounds__(256) void xz_mfma_kernel(
    const f16* __restrict__ Whi, const f16* __restrict__ Dt16,
    const float* __restrict__ bt, const float* __restrict__ alpha,
    const float* __restrict__ beta, bf16* __restrict__ XZ,
    float* __restrict__ bnsum, float* __restrict__ bnsumsq)
{
    const int b = blockIdx.z;
    const int m0 = blockIdx.y * 128;
    const int n0 = blockIdx.x * 128;
    const f16* __restrict__ Wb = Whi + (size_t)3 * CC * CC;   // Wt (hi)
    const f16* __restrict__ Db = Dt16 + (size_t)b * NN * CC;
    bf16* __restrict__ Zb = XZ + (size_t)b * CC * NN;

    __shared__ f16 Asl[128 * APAD];
    __shared__ f16 Bsl[128 * APAD];

    const int tid = threadIdx.x;
    const int wave = tid >> 6, lane = tid & 63;
    const int wr = (wave >> 1) * 64, wc = (wave & 1) * 64;
    const int lrow = lane & 15, lk = (lane >> 4) * 8;

    f32x4 acc[4][4] = {};

    for (int k0 = 0; k0 < CC; k0 += 32) {
#pragma unroll
        for (int i = 0; i < 2; ++i) {
            int idx = tid + 256 * i;
            int r = idx >> 2, ch = idx & 3;
            *(f16x8*)&Asl[r * APAD + ch * 8] =
                *(const f16x8*)&Wb[(size_t)(m0 + r) * CC + k0 + ch * 8];
            *(f16x8*)&Bsl[r * APAD + ch * 8] =
                *(const f16x8*)&Db[(size_t)(n0 + r) * CC + k0 + ch * 8];
        }
        __syncthreads();
        f16x8 af[4], bf[4];
#pragma unroll
        for (int i = 0; i < 4; ++i) {
            af[i] = *(const f16x8*)&Asl[(wr + i * 16 + lrow) * APAD + lk];
            bf[i] = *(const f16x8*)&Bsl[(wc + i * 16 + lrow) * APAD + lk];
        }
#pragma unroll
        for (int i = 0; i < 4; ++i)
#pragma unroll
            for (int j = 0; j < 4; ++j)
                acc[i][j] = __builtin_amdgcn_mfma_f32_16x16x32_f16(
                    af[i], bf[j], acc[i][j], 0, 0, 0);
        __syncthreads();
    }

#pragma unroll
    for (int i = 0; i < 4; ++i) {
#pragma unroll
        for (int q = 0; q < 4; ++q) {
            int o = m0 + wr + i * 16 + (lane >> 4) * 4 + q;
            float al = alpha[o], be = beta[o], bb = bt[o];
            float s1 = 0.f, s2 = 0.f;
#pragma unroll
            for (int j = 0; j < 4; ++j) {
                int n = n0 + wc + j * 16 + lrow;
                float z = al * (acc[i][j][q] + bb) + be;
                Zb[(size_t)o * NN + n] = __float2bfloat16(z);
                s1 += z; s2 += z * z;
            }
#pragma unroll
            for (int d = 1; d < 16; d <<= 1) {
                s1 += __shfl_xor(s1, d);
                s2 += __shfl_xor(s2, d);
            }
            if (lrow == 0) {
                atomicAdd(&bnsum[o], s1);
                atomicAdd(&bnsumsq[o], s2);
            }
        }
    }
}

// ---------------------------------------------------------------------------
// Kernel 7: out = x + relu(gamma*(XZ-mean)*rsqrt(var+eps)+beta)
// ---------------------------------------------------------------------------
__global__ __launch_bounds__(256) void final_kernel(
    const float* __restrict__ x, const bf16* __restrict__ XZ,
    const float* __restrict__ bnsum, const float* __restrict__ bnsumsq,
    const float* __restrict__ gamma, const float* __restrict__ bbeta,
    float* __restrict__ out)
{
    const int i4 = blockIdx.x * 256 + threadIdx.x;
    const int elem = i4 * 4;
    const int c = (elem / NN) % CC;
    const float inv_cnt = 1.f / (float)(BB * NN);
    const float mean = bnsum[c] * inv_cnt;
    const float var  = bnsumsq[c] * inv_cnt - mean * mean;
    const float rs = rsqrtf(var + BN_EPS);
    const float g = gamma[c], bb = bbeta[c];

    ushort4 zu = *(const ushort4*)&XZ[elem];
    float4 xv = *(const float4*)&x[elem];
    float z0 = bf2f(zu.x), z1 = bf2f(zu.y), z2 = bf2f(zu.z), z3 = bf2f(zu.w);
    float4 o;
    o.x = xv.x + fmaxf(g * (z0 - mean) * rs + bb, 0.f);
    o.y = xv.y + fmaxf(g * (z1 - mean) * rs + bb, 0.f);
    o.z = xv.z + fmaxf(g * (z2 - mean) * rs + bb, 0.f);
    o.w = xv.w + fmaxf(g * (z3 - mean) * rs + bb, 0.f);
    *(float4*)&out[elem] = o;
}

// ---------------------------------------------------------------------------

extern "C" void kernel_launch(void* const* d_in, const int* in_sizes, int n_in,
                              void* d_out, int out_size, void* d_ws, size_t ws_size,
                              hipStream_t stream) {
    const float* x     = (const float*)d_in[0];
    const float* Wq    = (const float*)d_in[1];
    const float* Wk    = (const float*)d_in[2];
    const float* Wv    = (const float*)d_in[3];
    const float* bv    = (const float*)d_in[4];
    const float* Wt    = (const float*)d_in[5];
    const float* bt    = (const float*)d_in[6];
    const float* gamma = (const float*)d_in[7];
    const float* bbeta = (const float*)d_in[8];
    const float* alpha = (const float*)d_in[9];
    const float* beta  = (const float*)d_in[10];
    float* out = (float*)d_out;

    const size_t BCN = (size_t)BB * CC * NN;   // 4,194,304 elements
    const size_t WSZ = (size_t)4 * CC * CC;    // 262,144

    f16* Whi = (f16*)d_ws;                     // 4 x [C][C] hi
    f16* Wlo = Whi + WSZ;                      // 4 x [C][C] lo
    bf16* Vb16 = (bf16*)(Wlo + WSZ);           // [B][C][N] bf16
    f16* Qhi = (f16*)(Vb16 + BCN);             // [B][N][C]
    f16* Khi = Qhi + BCN;                      // [B][N][C]
    bf16* AT16 = (bf16*)(Khi + BCN);           // [B][N][N] bf16 P^T = exp(E - m_t), transposed
    bf16* XZ = AT16 + (size_t)BB * NN * NN;    // [B][C][N] bf16
    float* colsum  = (float*)(XZ + BCN);       // [B][N]
    float* bnsum   = colsum + (size_t)BB * NN; // [C]
    float* bnsumsq = bnsum + CC;               // [C]
    float* rowmax_p = bnsumsq + CC;            // [B][32][N] fp32
    float* rowsum_p = rowmax_p + (size_t)BB * 32 * NN;
    float* smxG     = rowsum_p + (size_t)BB * 32 * NN;   // [B][N]
    float* sinvG    = smxG + (size_t)BB * NN;            // [B][N]

    // Dt16 overlays Qhi (dead after energy). Xhi/Xlo overlay AT16 (written
    // only by energy, which runs after proj has consumed Xhi/Xlo).
    f16* Dt16 = Qhi;
    f16* Xhi = (f16*)AT16;                     // [B][N][C]
    f16* Xlo = Xhi + BCN;                      // [B][N][C]

    hipMemsetAsync(bnsum, 0, 2 * CC * sizeof(float), stream);

    prep_w_kernel<<<dim3(4 * CC * CC / 2048), 256, 0, stream>>>(
        Wq, Wk, Wv, Wt, Whi, Wlo);
    prep_x_kernel<<<dim3(NN / 64, CC / 64, BB), 256, 0, stream>>>(x, Xhi, Xlo);
    proj_mfma_kernel<<<dim3(NN / 128, CC / 128, 3 * BB), 256, 0, stream>>>(
        Whi, Wlo, Xhi, Xlo, bv, Qhi, Khi, Vb16);
    energy_mfma_kernel<<<dim3(NN / 128, NN / 128, BB), 256, 0, stream>>>(
        Qhi, Khi, AT16, rowmax_p, rowsum_p);
    rowmerge_kernel<<<dim3(BB * NN / 256), 256, 0, stream>>>(
        rowmax_p, rowsum_p, smxG, sinvG);
    colsum_fvec_kernel<<<dim3(32, BB), 256, 0, stream>>>(
        AT16, rowmax_p, smxG, sinvG, colsum);
    xr_mfma_kernel<<<dim3(NN / 64, CC / 64, BB), 256, 0, stream>>>(
        Vb16, AT16, rowmax_p, smxG, sinvG, colsum, x, Dt16);
    xz_mfma_kernel<<<dim3(NN / 128, CC / 128, BB), 256, 0, stream>>>(
        Whi, Dt16, bt, alpha, beta, XZ, bnsum, bnsumsq);
    final_kernel<<<dim3((int)(BCN / 4 / 256)), 256, 0, stream>>>(
        x, XZ, bnsum, bnsumsq, gamma, bbeta, out);
}

// Round 16
// 229.185 us; speedup vs baseline: 1.1230x; 1.0096x over previous
//
#include <hip/hip_runtime.h>
#include <hip/hip_bf16.h>
#include <math.h>

#define BB 8
#define CC 256
#define NN 2048
static constexpr float BN_EPS = 1e-5f;

typedef _Float16 f16;
typedef f16 f16x4 __attribute__((ext_vector_type(4)));
typedef f16 f16x8 __attribute__((ext_vector_type(8)));
typedef float f32x4 __attribute__((ext_vector_type(4)));
typedef short s16x8 __attribute__((ext_vector_type(8)));     // 8 bf16 (MFMA operand)
typedef unsigned short u16x8 __attribute__((ext_vector_type(8)));  // 16B raw
typedef __hip_bfloat16 bf16;

#define APAD 40   // 16-bit-elem row stride (32 data + 8 pad) = 80B, 16B-aligned
#define XPAD 72   // 16-bit-elem row stride (64 data + 8 pad) = 144B, 16B-aligned

__device__ inline float bf2f(unsigned short u) {
    return __uint_as_float((unsigned)u << 16);
}

// ---------------------------------------------------------------------------
// Prep A: four C x C weight matrices -> hi/lo f16 planes (concatenated).
// ---------------------------------------------------------------------------
__global__ __launch_bounds__(256) void prep_w_kernel(
    const float* __restrict__ Wq, const float* __restrict__ Wk,
    const float* __restrict__ Wv, const float* __restrict__ Wt,
    f16* __restrict__ Whi, f16* __restrict__ Wlo)
{
    int idx = (blockIdx.x * 256 + threadIdx.x) * 8;   // over 4*C*C
    const float* s = (idx < 65536) ? Wq : (idx < 131072) ? Wk
                    : (idx < 196608) ? Wv : Wt;
    int off = idx & 65535;
    float4 a = *(const float4*)&s[off];
    float4 b = *(const float4*)&s[off + 4];
    float v[8] = {a.x, a.y, a.z, a.w, b.x, b.y, b.z, b.w};
    f16x8 h, l;
#pragma unroll
    for (int j = 0; j < 8; ++j) {
        f16 hh = (f16)v[j];
        f16 ll = (f16)(v[j] - (float)hh);
        h[j] = hh;
        l[j] = ll;
    }
    *(f16x8*)&Whi[idx] = h;
    *(f16x8*)&Wlo[idx] = l;
}

// ---------------------------------------------------------------------------
// Prep B: Xhi/Xlo[b][n][c] = split (f16) of x[b][c][n]  (LDS-tiled transpose)
// ---------------------------------------------------------------------------
__global__ __launch_bounds__(256) void prep_x_kernel(
    const float* __restrict__ x, f16* __restrict__ Xhi, f16* __restrict__ Xlo)
{
    const int b = blockIdx.z, c0 = blockIdx.y * 64, n0 = blockIdx.x * 64;
    const float* __restrict__ Xb = x + (size_t)b * CC * NN;
    f16* __restrict__ Oh = Xhi + (size_t)b * NN * CC;
    f16* __restrict__ Ol = Xlo + (size_t)b * NN * CC;
    __shared__ f16 Th[64][72];
    __shared__ f16 Tl[64][72];
    const int tid = threadIdx.x;
    const int r = tid >> 4, c4 = (tid & 15) * 4;
#pragma unroll
    for (int i = 0; i < 4; ++i) {
        int rr = r + i * 16;
        float4 v = *(const float4*)&Xb[(size_t)(c0 + rr) * NN + n0 + c4];
        float vv[4] = {v.x, v.y, v.z, v.w};
#pragma unroll
        for (int j = 0; j < 4; ++j) {
            f16 hh = (f16)vv[j];
            f16 ll = (f16)(vv[j] - (float)hh);
            Th[c4 + j][rr] = hh;
            Tl[c4 + j][rr] = ll;
        }
    }
    __syncthreads();
#pragma unroll
    for (int i = 0; i < 2; ++i) {
        int idx = tid + 256 * i;
        int n = idx >> 3, cg = (idx & 7) * 8;
        *(f16x8*)&Oh[(size_t)(n0 + n) * CC + c0 + cg] = *(f16x8*)&Th[n][cg];
        *(f16x8*)&Ol[(size_t)(n0 + n) * CC + c0 + cg] = *(f16x8*)&Tl[n][cg];
    }
}

// ---------------------------------------------------------------------------
// Kernel 1: projections. Q/K: split-precision (hi*hi + hi*lo + lo*hi) ->
// f16 [b][n][c]. V: hi-only -> bf16 [b][c][n] (+bv).
// ---------------------------------------------------------------------------
__global__ __launch_bounds__(256) void proj_mfma_kernel(
    const f16* __restrict__ Whi, const f16* __restrict__ Wlo,
    const f16* __restrict__ Xhi, const f16* __restrict__ Xlo,
    const float* __restrict__ bv,
    f16* __restrict__ Qhi, f16* __restrict__ Khi, bf16* __restrict__ Vb16)
{
    const int which = blockIdx.z >> 3;
    const int b     = blockIdx.z & 7;
    const f16* __restrict__ Wh = Whi + (size_t)which * CC * CC;
    const f16* __restrict__ Wl = Wlo + (size_t)which * CC * CC;
    const f16* __restrict__ Xh = Xhi + (size_t)b * NN * CC;
    const f16* __restrict__ Xl = Xlo + (size_t)b * NN * CC;

    const int m0 = blockIdx.y * 128;   // output channels
    const int n0 = blockIdx.x * 128;   // points

    __shared__ f16 Ah[128 * APAD];
    __shared__ f16 Al[128 * APAD];
    __shared__ f16 Bh[128 * APAD];
    __shared__ f16 Bl[128 * APAD];

    const int tid = threadIdx.x;
    const int wave = tid >> 6, lane = tid & 63;
    const int wr = (wave >> 1) * 64, wc = (wave & 1) * 64;
    const int lrow = lane & 15, lk = (lane >> 4) * 8;

    f32x4 acc[4][4] = {};

    for (int k0 = 0; k0 < CC; k0 += 32) {
#pragma unroll
        for (int i = 0; i < 2; ++i) {
            int idx = tid + 256 * i;
            int r = idx >> 2, ch = idx & 3;
            *(f16x8*)&Ah[r * APAD + ch * 8] =
                *(const f16x8*)&Wh[(size_t)(m0 + r) * CC + k0 + ch * 8];
            *(f16x8*)&Bh[r * APAD + ch * 8] =
                *(const f16x8*)&Xh[(size_t)(n0 + r) * CC + k0 + ch * 8];
            if (which < 2) {
                *(f16x8*)&Al[r * APAD + ch * 8] =
                    *(const f16x8*)&Wl[(size_t)(m0 + r) * CC + k0 + ch * 8];
                *(f16x8*)&Bl[r * APAD + ch * 8] =
                    *(const f16x8*)&Xl[(size_t)(n0 + r) * CC + k0 + ch * 8];
            }
        }
        __syncthreads();
        f16x8 ah[4], al[4], bh[4], bl[4];
#pragma unroll
        for (int i = 0; i < 4; ++i) {
            ah[i] = *(const f16x8*)&Ah[(wr + i * 16 + lrow) * APAD + lk];
            bh[i] = *(const f16x8*)&Bh[(wc + i * 16 + lrow) * APAD + lk];
        }
        if (which < 2) {
#pragma unroll
            for (int i = 0; i < 4; ++i) {
                al[i] = *(const f16x8*)&Al[(wr + i * 16 + lrow) * APAD + lk];
                bl[i] = *(const f16x8*)&Bl[(wc + i * 16 + lrow) * APAD + lk];
            }
        }
#pragma unroll
        for (int i = 0; i < 4; ++i)
#pragma unroll
            for (int j = 0; j < 4; ++j) {
                acc[i][j] = __builtin_amdgcn_mfma_f32_16x16x32_f16(
                    ah[i], bh[j], acc[i][j], 0, 0, 0);
                if (which < 2) {
                    acc[i][j] = __builtin_amdgcn_mfma_f32_16x16x32_f16(
                        ah[i], bl[j], acc[i][j], 0, 0, 0);
                    acc[i][j] = __builtin_amdgcn_mfma_f32_16x16x32_f16(
                        al[i], bh[j], acc[i][j], 0, 0, 0);
                }
            }
        __syncthreads();
    }

    if (which < 2) {
        f16* __restrict__ Oh = ((which == 0) ? Qhi : Khi) + (size_t)b * NN * CC;
#pragma unroll
        for (int i = 0; i < 4; ++i) {
            int cb = m0 + wr + i * 16 + (lane >> 4) * 4;
#pragma unroll
            for (int j = 0; j < 4; ++j) {
                int n = n0 + wc + j * 16 + lrow;
                f16x4 hv;
#pragma unroll
                for (int q = 0; q < 4; ++q) hv[q] = (f16)acc[i][j][q];
                *(f16x4*)&Oh[(size_t)n * CC + cb] = hv;
            }
        }
    } else {
        bf16* __restrict__ Vb = Vb16 + (size_t)b * CC * NN;
#pragma unroll
        for (int i = 0; i < 4; ++i) {
            int cb = m0 + wr + i * 16 + (lane >> 4) * 4;
#pragma unroll
            for (int q = 0; q < 4; ++q) {
                float bvv = bv[cb + q];
#pragma unroll
                for (int j = 0; j < 4; ++j) {
                    int n = n0 + wc + j * 16 + lrow;
                    Vb[(size_t)(cb + q) * NN + n] = __float2bfloat16(acc[i][j][q] + bvv);
                }
            }
        }
    }
}

// ---------------------------------------------------------------------------
// Kernel 2: energy + per-tile softmax: E = Q.K^T, per-(row, 64-col tile)
// max m_t / expsum s_t, stores P^T[b][m][n] = bf16(exp(E - m_t)) transposed
// via LDS. fp32 E never hits HBM.
// ---------------------------------------------------------------------------
__global__ __launch_bounds__(256) void energy_mfma_kernel(
    const f16* __restrict__ Qhi, const f16* __restrict__ Khi,
    bf16* __restrict__ AT16,
    float* __restrict__ rowmax_p, float* __restrict__ rowsum_p)
{
    const int b = blockIdx.z;
    const int n0 = blockIdx.y * 128;
    const int m0 = blockIdx.x * 128;
    const f16* __restrict__ Qh = Qhi + (size_t)b * NN * CC;
    const f16* __restrict__ Kh = Khi + (size_t)b * NN * CC;

    __shared__ f16 Ah[128 * APAD];
    __shared__ f16 Bh[128 * APAD];
    __shared__ bf16 Tt[64 * 136];   // transpose staging: [m-local][n-local]

    const int tid = threadIdx.x;
    const int wave = tid >> 6, lane = tid & 63;
    const int wr = (wave >> 1) * 64, wc = (wave & 1) * 64;
    const int lrow = lane & 15, lk = (lane >> 4) * 8;

    f32x4 acc[4][4] = {};

    for (int k0 = 0; k0 < CC; k0 += 32) {
#pragma unroll
        for (int i = 0; i < 2; ++i) {
            int idx = tid + 256 * i;
            int r = idx >> 2, ch = idx & 3;
            *(f16x8*)&Ah[r * APAD + ch * 8] =
                *(const f16x8*)&Qh[(size_t)(n0 + r) * CC + k0 + ch * 8];
            *(f16x8*)&Bh[r * APAD + ch * 8] =
                *(const f16x8*)&Kh[(size_t)(m0 + r) * CC + k0 + ch * 8];
        }
        __syncthreads();
        f16x8 af[4], bf[4];
#pragma unroll
        for (int i = 0; i < 4; ++i) {
            af[i] = *(const f16x8*)&Ah[(wr + i * 16 + lrow) * APAD + lk];
            bf[i] = *(const f16x8*)&Bh[(wc + i * 16 + lrow) * APAD + lk];
        }
#pragma unroll
        for (int i = 0; i < 4; ++i)
#pragma unroll
            for (int j = 0; j < 4; ++j)
                acc[i][j] = __builtin_amdgcn_mfma_f32_16x16x32_f16(
                    af[i], bf[j], acc[i][j], 0, 0, 0);
        __syncthreads();
    }

    // stats: overwrite acc with p = exp(v - tile-max); store m_t, s_t
    const int mt_w = (m0 + wc) >> 6;   // this wave's 64-col tile index
    float* __restrict__ RMP = rowmax_p + ((size_t)b * 32 + mt_w) * NN;
    float* __restrict__ RSP = rowsum_p + ((size_t)b * 32 + mt_w) * NN;
#pragma unroll
    for (int i = 0; i < 4; ++i)
#pragma unroll
        for (int q = 0; q < 4; ++q) {
            float v0 = acc[i][0][q], v1 = acc[i][1][q];
            float v2 = acc[i][2][q], v3 = acc[i][3][q];
            float mx = fmaxf(fmaxf(v0, v1), fmaxf(v2, v3));
#pragma unroll
            for (int d = 1; d < 16; d <<= 1) mx = fmaxf(mx, __shfl_xor(mx, d));
            float p0 = __expf(v0 - mx), p1 = __expf(v1 - mx);
            float p2 = __expf(v2 - mx), p3 = __expf(v3 - mx);
            acc[i][0][q] = p0; acc[i][1][q] = p1;
            acc[i][2][q] = p2; acc[i][3][q] = p3;
            float es = p0 + p1 + p2 + p3;
#pragma unroll
            for (int d = 1; d < 16; d <<= 1) es += __shfl_xor(es, d);
            if (lrow == 0) {
                int row = n0 + wr + i * 16 + (lane >> 4) * 4 + q;
                RMP[row] = mx;
                RSP[row] = es;
            }
        }

    // transposed bf16 store via LDS, two 64-col chunks
    bf16* __restrict__ Ab = AT16 + (size_t)b * NN * NN;   // [m][n]
    for (int chunk = 0; chunk < 2; ++chunk) {
        if ((wave & 1) == chunk) {
#pragma unroll
            for (int i = 0; i < 4; ++i)
#pragma unroll
                for (int j = 0; j < 4; ++j)
#pragma unroll
                    for (int q = 0; q < 4; ++q)
                        Tt[(j * 16 + lrow) * 136 + wr + i * 16 + (lane >> 4) * 4 + q] =
                            __float2bfloat16(acc[i][j][q]);
        }
        __syncthreads();
#pragma unroll
        for (int u = 0; u < 4; ++u) {
            int e = tid + u * 256;              // 0..1023
            int mrow = e >> 4, nch = (e & 15) * 8;
            *(u16x8*)&Ab[(size_t)(m0 + chunk * 64 + mrow) * NN + n0 + nch] =
                *(const u16x8*)&Tt[mrow * 136 + nch];
        }
        __syncthreads();
    }
}

// ---------------------------------------------------------------------------
// Kernel 2b: merge 32 per-tile row stats -> fvecG[b][t][n] =
// exp(m_t - gmx) / denom  (the complete softmax rescale factor per tile).
// ---------------------------------------------------------------------------
__global__ __launch_bounds__(256) void rowmerge_kernel(
    const float* __restrict__ rowmax_p, const float* __restrict__ rowsum_p,
    float* __restrict__ fvecG)
{
    int idx = blockIdx.x * 256 + threadIdx.x;   // b*NN + n
    int b = idx >> 11, n = idx & (NN - 1);
    const float* __restrict__ RM = rowmax_p + (size_t)b * 32 * NN + n;
    const float* __restrict__ RS = rowsum_p + (size_t)b * 32 * NN + n;
    float rm[32];
    float gmx = -1e30f;
#pragma unroll
    for (int t = 0; t < 32; ++t) {
        rm[t] = RM[(size_t)t * NN];
        gmx = fmaxf(gmx, rm[t]);
    }
    float s = 0.f;
#pragma unroll
    for (int t = 0; t < 32; ++t)
        s += RS[(size_t)t * NN] * __expf(rm[t] - gmx);
    const float inv = 1.f / s;
    float* __restrict__ FG = fvecG + (size_t)b * 32 * NN + n;
#pragma unroll
    for (int t = 0; t < 32; ++t)
        FG[(size_t)t * NN] = __expf(rm[t] - gmx) * inv;
}

// ---------------------------------------------------------------------------
// Kernel 4: colsum[m] = sum_n P^T[m][n] * fvecG[b][mt(m)][n].
// One block per (mt, b); block owns rows m = mt*64..+63 -> no atomics.
// ---------------------------------------------------------------------------
__global__ __launch_bounds__(256) void colsum_fvec_kernel(
    const bf16* __restrict__ AT16, const float* __restrict__ fvecG,
    float* __restrict__ colsum)
{
    const int mt = blockIdx.x, b = blockIdx.y;
    const bf16* __restrict__ Ab = AT16 + (size_t)b * NN * NN;
    const float* __restrict__ FG = fvecG + ((size_t)b * 32 + mt) * NN;
    const int tid = threadIdx.x;
    const int wave = tid >> 6, lane = tid & 63;

    // per-lane fvec registers for its 32 n-slots (k = p*512 + lane*8 + e)
    float fv[4][8];
#pragma unroll
    for (int p = 0; p < 4; ++p) {
        int k = p * 512 + lane * 8;
        float4 f0 = *(const float4*)&FG[k];
        float4 f1 = *(const float4*)&FG[k + 4];
        fv[p][0] = f0.x; fv[p][1] = f0.y; fv[p][2] = f0.z; fv[p][3] = f0.w;
        fv[p][4] = f1.x; fv[p][5] = f1.y; fv[p][6] = f1.z; fv[p][7] = f1.w;
    }

#pragma unroll
    for (int rr = 0; rr < 16; ++rr) {
        int m = mt * 64 + wave * 16 + rr;
        const bf16* __restrict__ R = &Ab[(size_t)m * NN];
        float cs = 0.f;
#pragma unroll
        for (int p = 0; p < 4; ++p) {
            int k = p * 512 + lane * 8;
            u16x8 v = *(const u16x8*)&R[k];
#pragma unroll
            for (int e = 0; e < 8; ++e)
                cs += bf2f((unsigned short)v[e]) * fv[p][e];
        }
#pragma unroll
        for (int d = 1; d < 64; d <<= 1) cs += __shfl_xor(cs, d);
        if (lane == 0) colsum[b * NN + m] = cs;
    }
}

// ---------------------------------------------------------------------------
// Kernel 5: x_r_raw = V . A^T. B-staging folds the fvecG rescale read from
// L2 (register float4s, no LDS table); rcv in epilogue; Dt16[n][c] out.
// ---------------------------------------------------------------------------
__global__ __launch_bounds__(256) void xr_mfma_kernel(
    const bf16* __restrict__ Vb16, const bf16* __restrict__ AT16,
    const float* __restrict__ fvecG, const float* __restrict__ colsum,
    const float* __restrict__ x, f16* __restrict__ Dt16)
{
    const int b  = blockIdx.z;
    const int c0 = blockIdx.y * 64;
    const int n0 = blockIdx.x * 64;   // output point tile (single mt)
    const bf16* __restrict__ Vb = Vb16 + (size_t)b * CC * NN;
    const bf16* __restrict__ Ab = AT16 + (size_t)b * NN * NN;
    const float* __restrict__ Xb = x + (size_t)b * CC * NN;
    const float* __restrict__ FG = fvecG + ((size_t)b * 32 + (n0 >> 6)) * NN;
    f16* __restrict__ Db = Dt16 + (size_t)b * NN * CC;

    __shared__ bf16 Asl[64 * XPAD];
    __shared__ bf16 Bsl[64 * XPAD];
    __shared__ float rcvL[64];

    const int tid = threadIdx.x;
    if (tid < 64) rcvL[tid] = 1.f / (1e-9f + colsum[b * NN + n0 + tid]);

    const int wave = tid >> 6, lane = tid & 63;
    const int wr = (wave >> 1) * 32, wc = (wave & 1) * 32;
    const int lrow = lane & 15, lk = (lane >> 4) * 8;
    const int ch8 = (tid & 7) * 8;

    f32x4 acc[2][2] = {};

    for (int k0 = 0; k0 < NN; k0 += 64) {
        // per-iter fvec registers (same 8 k-offsets for both staged rows)
        float4 f0 = *(const float4*)&FG[k0 + ch8];
        float4 f1 = *(const float4*)&FG[k0 + ch8 + 4];
        float fg[8] = {f0.x, f0.y, f0.z, f0.w, f1.x, f1.y, f1.z, f1.w};
#pragma unroll
        for (int i = 0; i < 2; ++i) {
            int idx = tid + 256 * i;
            int r = idx >> 3;
            *(u16x8*)&Asl[r * XPAD + ch8] =
                *(const u16x8*)&Vb[(size_t)(c0 + r) * NN + k0 + ch8];
            u16x8 v = *(const u16x8*)&Ab[(size_t)(n0 + r) * NN + k0 + ch8];
            bf16 w[8];
#pragma unroll
            for (int e = 0; e < 8; ++e)
                w[e] = __float2bfloat16(bf2f((unsigned short)v[e]) * fg[e]);
            *(u16x8*)&Bsl[r * XPAD + ch8] = *(const u16x8*)w;
        }
        __syncthreads();
#pragma unroll
        for (int ks = 0; ks < 2; ++ks) {
            s16x8 af[2], bf[2];
#pragma unroll
            for (int i = 0; i < 2; ++i) {
                af[i] = *(const s16x8*)&Asl[(wr + i * 16 + lrow) * XPAD + ks * 32 + lk];
                bf[i] = *(const s16x8*)&Bsl[(wc + i * 16 + lrow) * XPAD + ks * 32 + lk];
            }
#pragma unroll
            for (int i = 0; i < 2; ++i)
#pragma unroll
                for (int j = 0; j < 2; ++j)
                    acc[i][j] = __builtin_amdgcn_mfma_f32_16x16x32_bf16(
                        af[i], bf[j], acc[i][j], 0, 0, 0);
        }
        __syncthreads();
    }

#pragma unroll
    for (int i = 0; i < 2; ++i) {
        int cb = c0 + wr + i * 16 + (lane >> 4) * 4;
#pragma unroll
        for (int j = 0; j < 2; ++j) {
            int ln = wc + j * 16 + lrow;
            int n = n0 + ln;
            float rc = rcvL[ln];
            f16x4 dv;
#pragma unroll
            for (int q = 0; q < 4; ++q)
                dv[q] = (f16)(Xb[(size_t)(cb + q) * NN + n] - acc[i][j][q] * rc);
            *(f16x4*)&Db[(size_t)n * CC + cb] = dv;
        }
    }
}

// ---------------------------------------------------------------------------
// Kernel 6: XZ(bf16) = alpha*(Wt*Dt16 + bt) + beta; BN sums from fp32 values.
// ---------------------------------------------------------------------------
__global__ __launch_bounds__(256) void xz_mfma_kernel(
    const f16* __restrict__ Whi, const f16* __restrict__ Dt16,
    const float* __restrict__ bt, const float* __restrict__ alpha,
    const float* __restrict__ beta, bf16* __restrict__ XZ,
    float* __restrict__ bnsum, float* __restrict__ bnsumsq)
{
    const int b = blockIdx.z;
    const int m0 = blockIdx.y * 128;
    const int n0 = blockIdx.x * 128;
    const f16* __restrict__ Wb = Whi + (size_t)3 * CC * CC;   // Wt (hi)
    const f16* __restrict__ Db = Dt16 + (size_t)b * NN * CC;
    bf16* __restrict__ Zb = XZ + (size_t)b * CC * NN;

    __shared__ f16 Asl[128 * APAD];
    __shared__ f16 Bsl[128 * APAD];

    const int tid = threadIdx.x;
    const int wave = tid >> 6, lane = tid & 63;
    const int wr = (wave >> 1) * 64, wc = (wave & 1) * 64;
    const int lrow = lane & 15, lk = (lane >> 4) * 8;

    f32x4 acc[4][4] = {};

    for (int k0 = 0; k0 < CC; k0 += 32) {
#pragma unroll
        for (int i = 0; i < 2; ++i) {
            int idx = tid + 256 * i;
            int r = idx >> 2, ch = idx & 3;
            *(f16x8*)&Asl[r * APAD + ch * 8] =
                *(const f16x8*)&Wb[(size_t)(m0 + r) * CC + k0 + ch * 8];
            *(f16x8*)&Bsl[r * APAD + ch * 8] =
                *(const f16x8*)&Db[(size_t)(n0 + r) * CC + k0 + ch * 8];
        }
        __syncthreads();
        f16x8 af[4], bf[4];
#pragma unroll
        for (int i = 0; i < 4; ++i) {
            af[i] = *(const f16x8*)&Asl[(wr + i * 16 + lrow) * APAD + lk];
            bf[i] = *(const f16x8*)&Bsl[(wc + i * 16 + lrow) * APAD + lk];
        }
#pragma unroll
        for (int i = 0; i < 4; ++i)
#pragma unroll
            for (int j = 0; j < 4; ++j)
                acc[i][j] = __builtin_amdgcn_mfma_f32_16x16x32_f16(
                    af[i], bf[j], acc[i][j], 0, 0, 0);
        __syncthreads();
    }

#pragma unroll
    for (int i = 0; i < 4; ++i) {
#pragma unroll
        for (int q = 0; q < 4; ++q) {
            int o = m0 + wr + i * 16 + (lane >> 4) * 4 + q;
            float al = alpha[o], be = beta[o], bb = bt[o];
            float s1 = 0.f, s2 = 0.f;
#pragma unroll
            for (int j = 0; j < 4; ++j) {
                int n = n0 + wc + j * 16 + lrow;
                float z = al * (acc[i][j][q] + bb) + be;
                Zb[(size_t)o * NN + n] = __float2bfloat16(z);
                s1 += z; s2 += z * z;
            }
#pragma unroll
            for (int d = 1; d < 16; d <<= 1) {
                s1 += __shfl_xor(s1, d);
                s2 += __shfl_xor(s2, d);
            }
            if (lrow == 0) {
                atomicAdd(&bnsum[o], s1);
                atomicAdd(&bnsumsq[o], s2);
            }
        }
    }
}

// ---------------------------------------------------------------------------
// Kernel 7: out = x + relu(gamma*(XZ-mean)*rsqrt(var+eps)+beta)
// ---------------------------------------------------------------------------
__global__ __launch_bounds__(256) void final_kernel(
    const float* __restrict__ x, const bf16* __restrict__ XZ,
    const float* __restrict__ bnsum, const float* __restrict__ bnsumsq,
    const float* __restrict__ gamma, const float* __restrict__ bbeta,
    float* __restrict__ out)
{
    const int i4 = blockIdx.x * 256 + threadIdx.x;
    const int elem = i4 * 4;
    const int c = (elem / NN) % CC;
    const float inv_cnt = 1.f / (float)(BB * NN);
    const float mean = bnsum[c] * inv_cnt;
    const float var  = bnsumsq[c] * inv_cnt - mean * mean;
    const float rs = rsqrtf(var + BN_EPS);
    const float g = gamma[c], bb = bbeta[c];

    ushort4 zu = *(const ushort4*)&XZ[elem];
    float4 xv = *(const float4*)&x[elem];
    float z0 = bf2f(zu.x), z1 = bf2f(zu.y), z2 = bf2f(zu.z), z3 = bf2f(zu.w);
    float4 o;
    o.x = xv.x + fmaxf(g * (z0 - mean) * rs + bb, 0.f);
    o.y = xv.y + fmaxf(g * (z1 - mean) * rs + bb, 0.f);
    o.z = xv.z + fmaxf(g * (z2 - mean) * rs + bb, 0.f);
    o.w = xv.w + fmaxf(g * (z3 - mean) * rs + bb, 0.f);
    *(float4*)&out[elem] = o;
}

// ---------------------------------------------------------------------------

extern "C" void kernel_launch(void* const* d_in, const int* in_sizes, int n_in,
                              void* d_out, int out_size, void* d_ws, size_t ws_size,
                              hipStream_t stream) {
    const float* x     = (const float*)d_in[0];
    const float* Wq    = (const float*)d_in[1];
    const float* Wk    = (const float*)d_in[2];
    const float* Wv    = (const float*)d_in[3];
    const float* bv    = (const float*)d_in[4];
    const float* Wt    = (const float*)d_in[5];
    const float* bt    = (const float*)d_in[6];
    const float* gamma = (const float*)d_in[7];
    const float* bbeta = (const float*)d_in[8];
    const float* alpha = (const float*)d_in[9];
    const float* beta  = (const float*)d_in[10];
    float* out = (float*)d_out;

    const size_t BCN = (size_t)BB * CC * NN;   // 4,194,304 elements
    const size_t WSZ = (size_t)4 * CC * CC;    // 262,144

    f16* Whi = (f16*)d_ws;                     // 4 x [C][C] hi
    f16* Wlo = Whi + WSZ;                      // 4 x [C][C] lo
    bf16* Vb16 = (bf16*)(Wlo + WSZ);           // [B][C][N] bf16
    f16* Qhi = (f16*)(Vb16 + BCN);             // [B][N][C]
    f16* Khi = Qhi + BCN;                      // [B][N][C]
    bf16* AT16 = (bf16*)(Khi + BCN);           // [B][N][N] bf16 P^T
    bf16* XZ = AT16 + (size_t)BB * NN * NN;    // [B][C][N] bf16
    float* colsum  = (float*)(XZ + BCN);       // [B][N]
    float* bnsum   = colsum + (size_t)BB * NN; // [C]
    float* bnsumsq = bnsum + CC;               // [C]
    float* rowmax_p = bnsumsq + CC;            // [B][32][N] fp32
    float* rowsum_p = rowmax_p + (size_t)BB * 32 * NN;
    float* fvecG    = rowsum_p + (size_t)BB * 32 * NN;   // [B][32][N]

    // Dt16 overlays Qhi (dead after energy). Xhi/Xlo overlay AT16 (written
    // only by energy, which runs after proj has consumed Xhi/Xlo).
    f16* Dt16 = Qhi;
    f16* Xhi = (f16*)AT16;                     // [B][N][C]
    f16* Xlo = Xhi + BCN;                      // [B][N][C]

    hipMemsetAsync(bnsum, 0, 2 * CC * sizeof(float), stream);

    prep_w_kernel<<<dim3(4 * CC * CC / 2048), 256, 0, stream>>>(
        Wq, Wk, Wv, Wt, Whi, Wlo);
    prep_x_kernel<<<dim3(NN / 64, CC / 64, BB), 256, 0, stream>>>(x, Xhi, Xlo);
    proj_mfma_kernel<<<dim3(NN / 128, CC / 128, 3 * BB), 256, 0, stream>>>(
        Whi, Wlo, Xhi, Xlo, bv, Qhi, Khi, Vb16);
    energy_mfma_kernel<<<dim3(NN / 128, NN / 128, BB), 256, 0, stream>>>(
        Qhi, Khi, AT16, rowmax_p, rowsum_p);
    rowmerge_kernel<<<dim3(BB * NN / 256), 256, 0, stream>>>(
        rowmax_p, rowsum_p, fvecG);
    colsum_fvec_kernel<<<dim3(32, BB), 256, 0, stream>>>(
        AT16, fvecG, colsum);
    xr_mfma_kernel<<<dim3(NN / 64, CC / 64, BB), 256, 0, stream>>>(
        Vb16, AT16, fvecG, colsum, x, Dt16);
    xz_mfma_kernel<<<dim3(NN / 128, CC / 128, BB), 256, 0, stream>>>(
        Whi, Dt16, bt, alpha, beta, XZ, bnsum, bnsumsq);
    final_kernel<<<dim3((int)(BCN / 4 / 256)), 256, 0, stream>>>(
        x, XZ, bnsum, bnsumsq, gamma, bbeta, out);
}

// Round 17
// 186.320 us; speedup vs baseline: 1.3813x; 1.2301x over previous
//
#include <hip/hip_runtime.h>
#include <hip/hip_bf16.h>
#include <math.h>

#define BB 8
#define CC 256
#define NN 2048
static constexpr float BN_EPS = 1e-5f;

typedef _Float16 f16;
typedef f16 f16x4 __attribute__((ext_vector_type(4)));
typedef f16 f16x8 __attribute__((ext_vector_type(8)));
typedef float f32x4 __attribute__((ext_vector_type(4)));
typedef short s16x8 __attribute__((ext_vector_type(8)));     // 8 bf16 (MFMA operand)
typedef unsigned short u16x8 __attribute__((ext_vector_type(8)));  // 16B raw
typedef __hip_bfloat16 bf16;

#define APAD 40   // 16-bit-elem row stride (32 data + 8 pad) = 80B, 16B-aligned
#define XPAD 72   // 16-bit-elem row stride (64 data + 8 pad) = 144B, 16B-aligned

__device__ inline float bf2f(unsigned short u) {
    return __uint_as_float((unsigned)u << 16);
}

// ---------------------------------------------------------------------------
// Prep A: four C x C weight matrices -> f16 (hi only; concatenated).
// ---------------------------------------------------------------------------
__global__ __launch_bounds__(256) void prep_w_kernel(
    const float* __restrict__ Wq, const float* __restrict__ Wk,
    const float* __restrict__ Wv, const float* __restrict__ Wt,
    f16* __restrict__ Whi)
{
    int idx = (blockIdx.x * 256 + threadIdx.x) * 8;   // over 4*C*C
    const float* s = (idx < 65536) ? Wq : (idx < 131072) ? Wk
                    : (idx < 196608) ? Wv : Wt;
    int off = idx & 65535;
    float4 a = *(const float4*)&s[off];
    float4 b = *(const float4*)&s[off + 4];
    f16x8 h = {(f16)a.x, (f16)a.y, (f16)a.z, (f16)a.w,
               (f16)b.x, (f16)b.y, (f16)b.z, (f16)b.w};
    *(f16x8*)&Whi[idx] = h;
}

// ---------------------------------------------------------------------------
// Prep B: Xhi[b][n][c] = (f16) x[b][c][n]  (LDS-tiled transpose)
// ---------------------------------------------------------------------------
__global__ __launch_bounds__(256) void prep_x_kernel(
    const float* __restrict__ x, f16* __restrict__ Xhi)
{
    const int b = blockIdx.z, c0 = blockIdx.y * 64, n0 = blockIdx.x * 64;
    const float* __restrict__ Xb = x + (size_t)b * CC * NN;
    f16* __restrict__ Oh = Xhi + (size_t)b * NN * CC;
    __shared__ f16 Th[64][72];
    const int tid = threadIdx.x;
    const int r = tid >> 4, c4 = (tid & 15) * 4;
#pragma unroll
    for (int i = 0; i < 4; ++i) {
        int rr = r + i * 16;
        float4 v = *(const float4*)&Xb[(size_t)(c0 + rr) * NN + n0 + c4];
        Th[c4 + 0][rr] = (f16)v.x; Th[c4 + 1][rr] = (f16)v.y;
        Th[c4 + 2][rr] = (f16)v.z; Th[c4 + 3][rr] = (f16)v.w;
    }
    __syncthreads();
#pragma unroll
    for (int i = 0; i < 2; ++i) {
        int idx = tid + 256 * i;
        int n = idx >> 3, cg = (idx & 7) * 8;
        *(f16x8*)&Oh[(size_t)(n0 + n) * CC + c0 + cg] = *(f16x8*)&Th[n][cg];
    }
}

// ---------------------------------------------------------------------------
// Kernel 1: projections, hi-only MFMA. which 0/1 -> Qhi/Khi f16 [b][n][c];
// which 2 -> Vb16 bf16 [b][c][n] (+bv).
// ---------------------------------------------------------------------------
__global__ __launch_bounds__(256) void proj_mfma_kernel(
    const f16* __restrict__ Whi, const f16* __restrict__ Xhi,
    const float* __restrict__ bv,
    f16* __restrict__ Qhi, f16* __restrict__ Khi, bf16* __restrict__ Vb16)
{
    const int which = blockIdx.z >> 3;
    const int b     = blockIdx.z & 7;
    const f16* __restrict__ Wh = Whi + (size_t)which * CC * CC;
    const f16* __restrict__ Xh = Xhi + (size_t)b * NN * CC;

    const int m0 = blockIdx.y * 128;   // output channels
    const int n0 = blockIdx.x * 128;   // points

    __shared__ f16 Ah[128 * APAD];
    __shared__ f16 Bh[128 * APAD];

    const int tid = threadIdx.x;
    const int wave = tid >> 6, lane = tid & 63;
    const int wr = (wave >> 1) * 64, wc = (wave & 1) * 64;
    const int lrow = lane & 15, lk = (lane >> 4) * 8;

    f32x4 acc[4][4] = {};

    for (int k0 = 0; k0 < CC; k0 += 32) {
#pragma unroll
        for (int i = 0; i < 2; ++i) {
            int idx = tid + 256 * i;
            int r = idx >> 2, ch = idx & 3;
            *(f16x8*)&Ah[r * APAD + ch * 8] =
                *(const f16x8*)&Wh[(size_t)(m0 + r) * CC + k0 + ch * 8];
            *(f16x8*)&Bh[r * APAD + ch * 8] =
                *(const f16x8*)&Xh[(size_t)(n0 + r) * CC + k0 + ch * 8];
        }
        __syncthreads();
        f16x8 af[4], bf[4];
#pragma unroll
        for (int i = 0; i < 4; ++i) {
            af[i] = *(const f16x8*)&Ah[(wr + i * 16 + lrow) * APAD + lk];
            bf[i] = *(const f16x8*)&Bh[(wc + i * 16 + lrow) * APAD + lk];
        }
#pragma unroll
        for (int i = 0; i < 4; ++i)
#pragma unroll
            for (int j = 0; j < 4; ++j)
                acc[i][j] = __builtin_amdgcn_mfma_f32_16x16x32_f16(
                    af[i], bf[j], acc[i][j], 0, 0, 0);
        __syncthreads();
    }

    if (which < 2) {
        f16* __restrict__ Oh = ((which == 0) ? Qhi : Khi) + (size_t)b * NN * CC;
#pragma unroll
        for (int i = 0; i < 4; ++i) {
            int cb = m0 + wr + i * 16 + (lane >> 4) * 4;
#pragma unroll
            for (int j = 0; j < 4; ++j) {
                int n = n0 + wc + j * 16 + lrow;
                f16x4 hv;
#pragma unroll
                for (int q = 0; q < 4; ++q) hv[q] = (f16)acc[i][j][q];
                *(f16x4*)&Oh[(size_t)n * CC + cb] = hv;
            }
        }
    } else {
        bf16* __restrict__ Vb = Vb16 + (size_t)b * CC * NN;
#pragma unroll
        for (int i = 0; i < 4; ++i) {
            int cb = m0 + wr + i * 16 + (lane >> 4) * 4;
#pragma unroll
            for (int q = 0; q < 4; ++q) {
                float bvv = bv[cb + q];
#pragma unroll
                for (int j = 0; j < 4; ++j) {
                    int n = n0 + wc + j * 16 + lrow;
                    Vb[(size_t)(cb + q) * NN + n] = __float2bfloat16(acc[i][j][q] + bvv);
                }
            }
        }
    }
}

// ---------------------------------------------------------------------------
// Kernel 2: energy + per-tile softmax: E = Q.K^T, per-(row, 64-col tile)
// max m_t / expsum s_t, stores P^T[b][m][n] = bf16(exp(E - m_t)) transposed
// via LDS. fp32 E never hits HBM.
// ---------------------------------------------------------------------------
__global__ __launch_bounds__(256) void energy_mfma_kernel(
    const f16* __restrict__ Qhi, const f16* __restrict__ Khi,
    bf16* __restrict__ AT16,
    float* __restrict__ rowmax_p, float* __restrict__ rowsum_p)
{
    const int b = blockIdx.z;
    const int n0 = blockIdx.y * 128;
    const int m0 = blockIdx.x * 128;
    const f16* __restrict__ Qh = Qhi + (size_t)b * NN * CC;
    const f16* __restrict__ Kh = Khi + (size_t)b * NN * CC;

    __shared__ f16 Ah[128 * APAD];
    __shared__ f16 Bh[128 * APAD];
    __shared__ bf16 Tt[64 * 136];   // transpose staging: [m-local][n-local]

    const int tid = threadIdx.x;
    const int wave = tid >> 6, lane = tid & 63;
    const int wr = (wave >> 1) * 64, wc = (wave & 1) * 64;
    const int lrow = lane & 15, lk = (lane >> 4) * 8;

    f32x4 acc[4][4] = {};

    for (int k0 = 0; k0 < CC; k0 += 32) {
#pragma unroll
        for (int i = 0; i < 2; ++i) {
            int idx = tid + 256 * i;
            int r = idx >> 2, ch = idx & 3;
            *(f16x8*)&Ah[r * APAD + ch * 8] =
                *(const f16x8*)&Qh[(size_t)(n0 + r) * CC + k0 + ch * 8];
            *(f16x8*)&Bh[r * APAD + ch * 8] =
                *(const f16x8*)&Kh[(size_t)(m0 + r) * CC + k0 + ch * 8];
        }
        __syncthreads();
        f16x8 af[4], bf[4];
#pragma unroll
        for (int i = 0; i < 4; ++i) {
            af[i] = *(const f16x8*)&Ah[(wr + i * 16 + lrow) * APAD + lk];
            bf[i] = *(const f16x8*)&Bh[(wc + i * 16 + lrow) * APAD + lk];
        }
#pragma unroll
        for (int i = 0; i < 4; ++i)
#pragma unroll
            for (int j = 0; j < 4; ++j)
                acc[i][j] = __builtin_amdgcn_mfma_f32_16x16x32_f16(
                    af[i], bf[j], acc[i][j], 0, 0, 0);
        __syncthreads();
    }

    // stats: overwrite acc with p = exp(v - tile-max); store m_t, s_t
    const int mt_w = (m0 + wc) >> 6;   // this wave's 64-col tile index
    float* __restrict__ RMP = rowmax_p + ((size_t)b * 32 + mt_w) * NN;
    float* __restrict__ RSP = rowsum_p + ((size_t)b * 32 + mt_w) * NN;
#pragma unroll
    for (int i = 0; i < 4; ++i)
#pragma unroll
        for (int q = 0; q < 4; ++q) {
            float v0 = acc[i][0][q], v1 = acc[i][1][q];
            float v2 = acc[i][2][q], v3 = acc[i][3][q];
            float mx = fmaxf(fmaxf(v0, v1), fmaxf(v2, v3));
#pragma unroll
            for (int d = 1; d < 16; d <<= 1) mx = fmaxf(mx, __shfl_xor(mx, d));
            float p0 = __expf(v0 - mx), p1 = __expf(v1 - mx);
            float p2 = __expf(v2 - mx), p3 = __expf(v3 - mx);
            acc[i][0][q] = p0; acc[i][1][q] = p1;
            acc[i][2][q] = p2; acc[i][3][q] = p3;
            float es = p0 + p1 + p2 + p3;
#pragma unroll
            for (int d = 1; d < 16; d <<= 1) es += __shfl_xor(es, d);
            if (lrow == 0) {
                int row = n0 + wr + i * 16 + (lane >> 4) * 4 + q;
                RMP[row] = mx;
                RSP[row] = es;
            }
        }

    // transposed bf16 store via LDS, two 64-col chunks
    bf16* __restrict__ Ab = AT16 + (size_t)b * NN * NN;   // [m][n]
    for (int chunk = 0; chunk < 2; ++chunk) {
        if ((wave & 1) == chunk) {
#pragma unroll
            for (int i = 0; i < 4; ++i)
#pragma unroll
                for (int j = 0; j < 4; ++j)
#pragma unroll
                    for (int q = 0; q < 4; ++q)
                        Tt[(j * 16 + lrow) * 136 + wr + i * 16 + (lane >> 4) * 4 + q] =
                            __float2bfloat16(acc[i][j][q]);
        }
        __syncthreads();
#pragma unroll
        for (int u = 0; u < 4; ++u) {
            int e = tid + u * 256;              // 0..1023
            int mrow = e >> 4, nch = (e & 15) * 8;
            *(u16x8*)&Ab[(size_t)(m0 + chunk * 64 + mrow) * NN + n0 + nch] =
                *(const u16x8*)&Tt[mrow * 136 + nch];
        }
        __syncthreads();
    }
}

// ---------------------------------------------------------------------------
// Kernel 2b: merge 32 per-tile row stats -> fvecG[b][t][n] =
// exp(m_t - gmx) / denom  (the complete softmax rescale factor per tile).
// ---------------------------------------------------------------------------
__global__ __launch_bounds__(256) void rowmerge_kernel(
    const float* __restrict__ rowmax_p, const float* __restrict__ rowsum_p,
    float* __restrict__ fvecG)
{
    int idx = blockIdx.x * 256 + threadIdx.x;   // b*NN + n
    int b = idx >> 11, n = idx & (NN - 1);
    const float* __restrict__ RM = rowmax_p + (size_t)b * 32 * NN + n;
    const float* __restrict__ RS = rowsum_p + (size_t)b * 32 * NN + n;
    float rm[32];
    float gmx = -1e30f;
#pragma unroll
    for (int t = 0; t < 32; ++t) {
        rm[t] = RM[(size_t)t * NN];
        gmx = fmaxf(gmx, rm[t]);
    }
    float s = 0.f;
#pragma unroll
    for (int t = 0; t < 32; ++t)
        s += RS[(size_t)t * NN] * __expf(rm[t] - gmx);
    const float inv = 1.f / s;
    float* __restrict__ FG = fvecG + (size_t)b * 32 * NN + n;
#pragma unroll
    for (int t = 0; t < 32; ++t)
        FG[(size_t)t * NN] = __expf(rm[t] - gmx) * inv;
}

// ---------------------------------------------------------------------------
// Kernel 5: x_r_raw = V . A^T with colsum computed IN-KERNEL during
// B-staging (each thread accumulates its staged fvec-scaled values; 8-lane
// shuffle tree + LDS; all c-tile blocks compute identical sums). rcv in
// epilogue; Dt16[n][c] out.
// ---------------------------------------------------------------------------
__global__ __launch_bounds__(256) void xr_mfma_kernel(
    const bf16* __restrict__ Vb16, const bf16* __restrict__ AT16,
    const float* __restrict__ fvecG, const float* __restrict__ x,
    f16* __restrict__ Dt16)
{
    const int b  = blockIdx.z;
    const int c0 = blockIdx.y * 64;
    const int n0 = blockIdx.x * 64;   // output point tile (single mt)
    const bf16* __restrict__ Vb = Vb16 + (size_t)b * CC * NN;
    const bf16* __restrict__ Ab = AT16 + (size_t)b * NN * NN;
    const float* __restrict__ Xb = x + (size_t)b * CC * NN;
    const float* __restrict__ FG = fvecG + ((size_t)b * 32 + (n0 >> 6)) * NN;
    f16* __restrict__ Db = Dt16 + (size_t)b * NN * CC;

    __shared__ bf16 Asl[64 * XPAD];
    __shared__ bf16 Bsl[64 * XPAD];
    __shared__ float csL[64];

    const int tid = threadIdx.x;
    const int wave = tid >> 6, lane = tid & 63;
    const int wr = (wave >> 1) * 32, wc = (wave & 1) * 32;
    const int lrow = lane & 15, lk = (lane >> 4) * 8;
    const int ch8 = (tid & 7) * 8;
    const int r0 = tid >> 3;          // 0..31

    float cs0 = 0.f, cs1 = 0.f;
    f32x4 acc[2][2] = {};

    for (int k0 = 0; k0 < NN; k0 += 64) {
        float4 f0 = *(const float4*)&FG[k0 + ch8];
        float4 f1 = *(const float4*)&FG[k0 + ch8 + 4];
        float fg[8] = {f0.x, f0.y, f0.z, f0.w, f1.x, f1.y, f1.z, f1.w};
        {   // rows r0 (cs0) and r0+32 (cs1)
            *(u16x8*)&Asl[r0 * XPAD + ch8] =
                *(const u16x8*)&Vb[(size_t)(c0 + r0) * NN + k0 + ch8];
            u16x8 v = *(const u16x8*)&Ab[(size_t)(n0 + r0) * NN + k0 + ch8];
            bf16 w[8];
#pragma unroll
            for (int e = 0; e < 8; ++e) {
                float pv = bf2f((unsigned short)v[e]) * fg[e];
                w[e] = __float2bfloat16(pv);
                cs0 += pv;
            }
            *(u16x8*)&Bsl[r0 * XPAD + ch8] = *(const u16x8*)w;
        }
        {
            int r = r0 + 32;
            *(u16x8*)&Asl[r * XPAD + ch8] =
                *(const u16x8*)&Vb[(size_t)(c0 + r) * NN + k0 + ch8];
            u16x8 v = *(const u16x8*)&Ab[(size_t)(n0 + r) * NN + k0 + ch8];
            bf16 w[8];
#pragma unroll
            for (int e = 0; e < 8; ++e) {
                float pv = bf2f((unsigned short)v[e]) * fg[e];
                w[e] = __float2bfloat16(pv);
                cs1 += pv;
            }
            *(u16x8*)&Bsl[r * XPAD + ch8] = *(const u16x8*)w;
        }
        __syncthreads();
#pragma unroll
        for (int ks = 0; ks < 2; ++ks) {
            s16x8 af[2], bf[2];
#pragma unroll
            for (int i = 0; i < 2; ++i) {
                af[i] = *(const s16x8*)&Asl[(wr + i * 16 + lrow) * XPAD + ks * 32 + lk];
                bf[i] = *(const s16x8*)&Bsl[(wc + i * 16 + lrow) * XPAD + ks * 32 + lk];
            }
#pragma unroll
            for (int i = 0; i < 2; ++i)
#pragma unroll
                for (int j = 0; j < 2; ++j)
                    acc[i][j] = __builtin_amdgcn_mfma_f32_16x16x32_bf16(
                        af[i], bf[j], acc[i][j], 0, 0, 0);
        }
        __syncthreads();
    }

    // reduce colsum partials across the 8 lanes sharing each row
    cs0 += __shfl_xor(cs0, 1); cs0 += __shfl_xor(cs0, 2); cs0 += __shfl_xor(cs0, 4);
    cs1 += __shfl_xor(cs1, 1); cs1 += __shfl_xor(cs1, 2); cs1 += __shfl_xor(cs1, 4);
    if ((lane & 7) == 0) {
        csL[r0] = cs0;
        csL[r0 + 32] = cs1;
    }
    __syncthreads();

#pragma unroll
    for (int i = 0; i < 2; ++i) {
        int cb = c0 + wr + i * 16 + (lane >> 4) * 4;
#pragma unroll
        for (int j = 0; j < 2; ++j) {
            int ln = wc + j * 16 + lrow;
            int n = n0 + ln;
            float rc = 1.f / (1e-9f + csL[ln]);
            f16x4 dv;
#pragma unroll
            for (int q = 0; q < 4; ++q)
                dv[q] = (f16)(Xb[(size_t)(cb + q) * NN + n] - acc[i][j][q] * rc);
            *(f16x4*)&Db[(size_t)n * CC + cb] = dv;
        }
    }
}

// ---------------------------------------------------------------------------
// Kernel 6: XZ(bf16) = alpha*(Wt*Dt16 + bt) + beta; BN sums from fp32 values.
// ---------------------------------------------------------------------------
__global__ __launch_bounds__(256) void xz_mfma_kernel(
    const f16* __restrict__ Whi, const f16* __restrict__ Dt16,
    const float* __restrict__ bt, const float* __restrict__ alpha,
    const float* __restrict__ beta, bf16* __restrict__ XZ,
    float* __restrict__ bnsum, float* __restrict__ bnsumsq)
{
    const int b = blockIdx.z;
    const int m0 = blockIdx.y * 128;
    const int n0 = blockIdx.x * 128;
    const f16* __restrict__ Wb = Whi + (size_t)3 * CC * CC;   // Wt
    const f16* __restrict__ Db = Dt16 + (size_t)b * NN * CC;
    bf16* __restrict__ Zb = XZ + (size_t)b * CC * NN;

    __shared__ f16 Asl[128 * APAD];
    __shared__ f16 Bsl[128 * APAD];

    const int tid = threadIdx.x;
    const int wave = tid >> 6, lane = tid & 63;
    const int wr = (wave >> 1) * 64, wc = (wave & 1) * 64;
    const int lrow = lane & 15, lk = (lane >> 4) * 8;

    f32x4 acc[4][4] = {};

    for (int k0 = 0; k0 < CC; k0 += 32) {
#pragma unroll
        for (int i = 0; i < 2; ++i) {
            int idx = tid + 256 * i;
            int r = idx >> 2, ch = idx & 3;
            *(f16x8*)&Asl[r * APAD + ch * 8] =
                *(const f16x8*)&Wb[(size_t)(m0 + r) * CC + k0 + ch * 8];
            *(f16x8*)&Bsl[r * APAD + ch * 8] =
                *(const f16x8*)&Db[(size_t)(n0 + r) * CC + k0 + ch * 8];
        }
        __syncthreads();
        f16x8 af[4], bf[4];
#pragma unroll
        for (int i = 0; i < 4; ++i) {
            af[i] = *(const f16x8*)&Asl[(wr + i * 16 + lrow) * APAD + lk];
            bf[i] = *(const f16x8*)&Bsl[(wc + i * 16 + lrow) * APAD + lk];
        }
#pragma unroll
        for (int i = 0; i < 4; ++i)
#pragma unroll
            for (int j = 0; j < 4; ++j)
                acc[i][j] = __builtin_amdgcn_mfma_f32_16x16x32_f16(
                    af[i], bf[j], acc[i][j], 0, 0, 0);
        __syncthreads();
    }

#pragma unroll
    for (int i = 0; i < 4; ++i) {
#pragma unroll
        for (int q = 0; q < 4; ++q) {
            int o = m0 + wr + i * 16 + (lane >> 4) * 4 + q;
            float al = alpha[o], be = beta[o], bb = bt[o];
            float s1 = 0.f, s2 = 0.f;
#pragma unroll
            for (int j = 0; j < 4; ++j) {
                int n = n0 + wc + j * 16 + lrow;
                float z = al * (acc[i][j][q] + bb) + be;
                Zb[(size_t)o * NN + n] = __float2bfloat16(z);
                s1 += z; s2 += z * z;
            }
#pragma unroll
            for (int d = 1; d < 16; d <<= 1) {
                s1 += __shfl_xor(s1, d);
                s2 += __shfl_xor(s2, d);
            }
            if (lrow == 0) {
                atomicAdd(&bnsum[o], s1);
                atomicAdd(&bnsumsq[o], s2);
            }
        }
    }
}

// ---------------------------------------------------------------------------
// Kernel 7: out = x + relu(gamma*(XZ-mean)*rsqrt(var+eps)+beta)
// ---------------------------------------------------------------------------
__global__ __launch_bounds__(256) void final_kernel(
    const float* __restrict__ x, const bf16* __restrict__ XZ,
    const float* __restrict__ bnsum, const float* __restrict__ bnsumsq,
    const float* __restrict__ gamma, const float* __restrict__ bbeta,
    float* __restrict__ out)
{
    const int i4 = blockIdx.x * 256 + threadIdx.x;
    const int elem = i4 * 4;
    const int c = (elem / NN) % CC;
    const float inv_cnt = 1.f / (float)(BB * NN);
    const float mean = bnsum[c] * inv_cnt;
    const float var  = bnsumsq[c] * inv_cnt - mean * mean;
    const float rs = rsqrtf(var + BN_EPS);
    const float g = gamma[c], bb = bbeta[c];

    ushort4 zu = *(const ushort4*)&XZ[elem];
    float4 xv = *(const float4*)&x[elem];
    float z0 = bf2f(zu.x), z1 = bf2f(zu.y), z2 = bf2f(zu.z), z3 = bf2f(zu.w);
    float4 o;
    o.x = xv.x + fmaxf(g * (z0 - mean) * rs + bb, 0.f);
    o.y = xv.y + fmaxf(g * (z1 - mean) * rs + bb, 0.f);
    o.z = xv.z + fmaxf(g * (z2 - mean) * rs + bb, 0.f);
    o.w = xv.w + fmaxf(g * (z3 - mean) * rs + bb, 0.f);
    *(float4*)&out[elem] = o;
}

// ---------------------------------------------------------------------------

extern "C" void kernel_launch(void* const* d_in, const int* in_sizes, int n_in,
                              void* d_out, int out_size, void* d_ws, size_t ws_size,
                              hipStream_t stream) {
    const float* x     = (const float*)d_in[0];
    const float* Wq    = (const float*)d_in[1];
    const float* Wk    = (const float*)d_in[2];
    const float* Wv    = (const float*)d_in[3];
    const float* bv    = (const float*)d_in[4];
    const float* Wt    = (const float*)d_in[5];
    const float* bt    = (const float*)d_in[6];
    const float* gamma = (const float*)d_in[7];
    const float* bbeta = (const float*)d_in[8];
    const float* alpha = (const float*)d_in[9];
    const float* beta  = (const float*)d_in[10];
    float* out = (float*)d_out;

    const size_t BCN = (size_t)BB * CC * NN;   // 4,194,304 elements
    const size_t WSZ = (size_t)4 * CC * CC;    // 262,144

    f16* Whi = (f16*)d_ws;                     // 4 x [C][C] f16
    bf16* Vb16 = (bf16*)(Whi + WSZ);           // [B][C][N] bf16
    f16* Qhi = (f16*)(Vb16 + BCN);             // [B][N][C]
    f16* Khi = Qhi + BCN;                      // [B][N][C]
    bf16* AT16 = (bf16*)(Khi + BCN);           // [B][N][N] bf16 P^T
    bf16* XZ = AT16 + (size_t)BB * NN * NN;    // [B][C][N] bf16
    float* bnsum   = (float*)(XZ + BCN);       // [C]
    float* bnsumsq = bnsum + CC;               // [C]
    float* rowmax_p = bnsumsq + CC;            // [B][32][N] fp32
    float* rowsum_p = rowmax_p + (size_t)BB * 32 * NN;
    float* fvecG    = rowsum_p + (size_t)BB * 32 * NN;   // [B][32][N]

    // Dt16 overlays Qhi (dead after energy). Xhi overlays AT16 (written
    // only by energy, which runs after proj has consumed Xhi).
    f16* Dt16 = Qhi;
    f16* Xhi = (f16*)AT16;                     // [B][N][C]

    hipMemsetAsync(bnsum, 0, 2 * CC * sizeof(float), stream);

    prep_w_kernel<<<dim3(4 * CC * CC / 2048), 256, 0, stream>>>(
        Wq, Wk, Wv, Wt, Whi);
    prep_x_kernel<<<dim3(NN / 64, CC / 64, BB), 256, 0, stream>>>(x, Xhi);
    proj_mfma_kernel<<<dim3(NN / 128, CC / 128, 3 * BB), 256, 0, stream>>>(
        Whi, Xhi, bv, Qhi, Khi, Vb16);
    energy_mfma_kernel<<<dim3(NN / 128, NN / 128, BB), 256, 0, stream>>>(
        Qhi, Khi, AT16, rowmax_p, rowsum_p);
    rowmerge_kernel<<<dim3(BB * NN / 256), 256, 0, stream>>>(
        rowmax_p, rowsum_p, fvecG);
    xr_mfma_kernel<<<dim3(NN / 64, CC / 64, BB), 256, 0, stream>>>(
        Vb16, AT16, fvecG, x, Dt16);
    xz_mfma_kernel<<<dim3(NN / 128, CC / 128, BB), 256, 0, stream>>>(
        Whi, Dt16, bt, alpha, beta, XZ, bnsum, bnsumsq);
    final_kernel<<<dim3((int)(BCN / 4 / 256)), 256, 0, stream>>>(
        x, XZ, bnsum, bnsumsq, gamma, bbeta, out);
}